// Round 1
// baseline (19136.458 us; speedup 1.0000x reference)
//
#include <hip/hip_runtime.h>

#define V_ 32000
#define E_ 256
#define H_ 512
#define B_ 32
#define S_ 128
#define T_ 64
#define TD_ 63        // decoder steps (T-1)
#define G3_ 1536      // 3*H
#define CATK_ 1792    // H + E + 2H
#define DIN_ 1280     // E + 2H

// ---------------------------------------------------------------------------
// prep: token permutations + zero encoder hidden state
// ---------------------------------------------------------------------------
__global__ __launch_bounds__(256)
void prep_kernel(const int* __restrict__ src, const int* __restrict__ tgt,
                 int* __restrict__ tokf, int* __restrict__ tokb, int* __restrict__ tokd,
                 float* __restrict__ h_enc)
{
    int tid = blockIdx.x * 256 + threadIdx.x;
    if (tid < S_ * B_) {
        int s = tid >> 5, b = tid & 31;
        tokf[tid] = src[b * S_ + s];
        tokb[tid] = src[b * S_ + (S_ - 1 - s)];
    }
    if (tid < TD_ * B_) {
        int t = tid >> 5, b = tid & 31;
        tokd[tid] = tgt[b * T_ + t];
    }
    if (tid < 2 * 2 * B_ * H_) h_enc[tid] = 0.f;   // [dir][pp][B][H]
}

// ---------------------------------------------------------------------------
// write decoder embeddings into cat[:, 512:768] (independent of recurrence)
// ---------------------------------------------------------------------------
__global__ __launch_bounds__(256)
void emb_cat_kernel(const int* __restrict__ tokd, const float* __restrict__ dec_emb,
                    float* __restrict__ cat)
{
    int row = blockIdx.x;          // row = t*32 + b, 0..2015
    int tid = threadIdx.x;         // 0..255 == E_
    cat[(size_t)row * CATK_ + H_ + tid] = dec_emb[(size_t)tokd[row] * E_ + tid];
}

// ---------------------------------------------------------------------------
// Generic fp32 GEMM: C[m][n] = sum_k Arow(m)[k] * W[n][k] + bias[n]
//  - GATHER: Arow(m) = emb + tokens[m]*K   (embedding gather, K==E_)
//  - FC1MAP: output row m=t*32+b goes to C + ((b*T_+t)*ldc)   (fc1 -> d_out)
// 128x128 tile, K-step 16, 256 threads, 8x8 per thread.
// Requires N % 128 == 0, K % 16 == 0. M guarded (row clamp + store guard).
// ---------------------------------------------------------------------------
template<int GATHER, int FC1MAP>
__global__ __launch_bounds__(256)
void gemm128_kernel(const float* __restrict__ A, int lda,
                    const int* __restrict__ tokens, const float* __restrict__ emb,
                    const float* __restrict__ W, int ldw,
                    const float* __restrict__ bias,
                    float* __restrict__ C, int ldc,
                    int M, int N, int K)
{
    __shared__ float As[16][132];
    __shared__ float Ws[16][132];
    (void)N;
    int tid = threadIdx.x;
    int m0 = blockIdx.y * 128, n0 = blockIdx.x * 128;
    int tx = tid & 15, ty = tid >> 4;
    float c[8][8];
#pragma unroll
    for (int i = 0; i < 8; i++)
#pragma unroll
        for (int j = 0; j < 8; j++) c[i][j] = 0.f;

    int arow = tid >> 1;            // 0..127
    int kq = (tid & 1) * 8;

    int am = m0 + arow; if (am >= M) am = M - 1;
    const float* arp;
    if (GATHER) arp = emb + (size_t)tokens[am] * (size_t)K;
    else        arp = A + (size_t)am * (size_t)lda;
    const float* wrp = W + (size_t)(n0 + arow) * (size_t)ldw;

    for (int kb = 0; kb < K; kb += 16) {
        __syncthreads();
        float4 a0 = *(const float4*)(arp + kb + kq);
        float4 a1 = *(const float4*)(arp + kb + kq + 4);
        float4 w0 = *(const float4*)(wrp + kb + kq);
        float4 w1 = *(const float4*)(wrp + kb + kq + 4);
        As[kq + 0][arow] = a0.x; As[kq + 1][arow] = a0.y;
        As[kq + 2][arow] = a0.z; As[kq + 3][arow] = a0.w;
        As[kq + 4][arow] = a1.x; As[kq + 5][arow] = a1.y;
        As[kq + 6][arow] = a1.z; As[kq + 7][arow] = a1.w;
        Ws[kq + 0][arow] = w0.x; Ws[kq + 1][arow] = w0.y;
        Ws[kq + 2][arow] = w0.z; Ws[kq + 3][arow] = w0.w;
        Ws[kq + 4][arow] = w1.x; Ws[kq + 5][arow] = w1.y;
        Ws[kq + 6][arow] = w1.z; Ws[kq + 7][arow] = w1.w;
        __syncthreads();
#pragma unroll
        for (int kk = 0; kk < 16; kk++) {
            float a[8], bb[8];
            *(float4*)&a[0]  = *(const float4*)&As[kk][ty * 8];
            *(float4*)&a[4]  = *(const float4*)&As[kk][ty * 8 + 4];
            *(float4*)&bb[0] = *(const float4*)&Ws[kk][tx * 8];
            *(float4*)&bb[4] = *(const float4*)&Ws[kk][tx * 8 + 4];
#pragma unroll
            for (int i = 0; i < 8; i++)
#pragma unroll
                for (int j = 0; j < 8; j++) c[i][j] += a[i] * bb[j];
        }
    }

#pragma unroll
    for (int i = 0; i < 8; i++) {
        int m = m0 + ty * 8 + i;
        if (m < M) {
            size_t rowoff;
            if (FC1MAP) { int tt = m >> 5, bb2 = m & 31; rowoff = ((size_t)bb2 * T_ + tt) * (size_t)ldc; }
            else        rowoff = (size_t)m * (size_t)ldc;
#pragma unroll
            for (int j = 0; j < 8; j += 4) {
                int n = n0 + tx * 8 + j;
                float4 v;
                v.x = c[i][j + 0] + bias[n + 0];
                v.y = c[i][j + 1] + bias[n + 1];
                v.z = c[i][j + 2] + bias[n + 2];
                v.w = c[i][j + 3] + bias[n + 3];
                *(float4*)(C + rowoff + n) = v;
            }
        }
    }
}

// ---------------------------------------------------------------------------
// one bi-GRU encoder step (both directions). grid = 128: [dir 2][bhalf 2][kc 32]
// thread = (bl 16, kl 16): computes h'[b][k] via 3 dot-512 over h (LDS).
// ---------------------------------------------------------------------------
__global__ __launch_bounds__(256)
void enc_step_kernel(const float* __restrict__ gxf, const float* __restrict__ gxb,
                     const float* __restrict__ Whh_f, const float* __restrict__ bhh_f,
                     const float* __restrict__ Whh_b, const float* __restrict__ bhh_b,
                     float* __restrict__ h_enc, float* __restrict__ enc_bt, int t)
{
    int bx = blockIdx.x;
    int dir = bx >> 6;
    int bh  = (bx >> 5) & 1;
    int kc  = bx & 31;
    int tid = threadIdx.x;
    int bl = tid & 15;
    int kl = tid >> 4;
    int b = bh * 16 + bl;
    int k = kc * 16 + kl;
    const float* Whh = dir ? Whh_b : Whh_f;
    const float* bhh = dir ? bhh_b : bhh_f;
    const float* gx  = dir ? gxb : gxf;
    int pp = t & 1;
    const float* hin  = h_enc + (size_t)(dir * 2 + pp) * B_ * H_;
    float* hout = h_enc + (size_t)(dir * 2 + (1 - pp)) * B_ * H_;

    __shared__ float hL[16 * 516];   // 16 rows of h, padded stride 516 (bank spread)
    {
        const float* hsrc = hin + (size_t)bh * 16 * H_;
        for (int i = tid * 4; i < 16 * H_; i += 1024) {
            int r = i >> 9;
            int cix = i & (H_ - 1);
            float4 v = *(const float4*)(hsrc + i);
            *(float4*)&hL[r * 516 + cix] = v;
        }
    }
    __syncthreads();

    const float* wr = Whh + (size_t)k * H_;
    const float* wz = Whh + (size_t)(H_ + k) * H_;
    const float* wn = Whh + (size_t)(2 * H_ + k) * H_;
    const float* hv = &hL[bl * 516];
    float ar = 0.f, az = 0.f, an = 0.f;
#pragma unroll 4
    for (int j = 0; j < H_; j += 4) {
        float4 h4 = *(const float4*)(hv + j);
        float4 r4 = *(const float4*)(wr + j);
        float4 z4 = *(const float4*)(wz + j);
        float4 n4 = *(const float4*)(wn + j);
        ar += h4.x * r4.x + h4.y * r4.y + h4.z * r4.z + h4.w * r4.w;
        az += h4.x * z4.x + h4.y * z4.y + h4.z * z4.z + h4.w * z4.w;
        an += h4.x * n4.x + h4.y * n4.y + h4.z * n4.z + h4.w * n4.w;
    }
    const float* gxr = gx + ((size_t)t * B_ + b) * G3_;
    float xr = gxr[k], xz = gxr[H_ + k], xn = gxr[2 * H_ + k];
    float hr = ar + bhh[k], hz = az + bhh[H_ + k], hn = an + bhh[2 * H_ + k];
    float rg = 1.f / (1.f + expf(-(xr + hr)));
    float zg = 1.f / (1.f + expf(-(xz + hz)));
    float ng = tanhf(xn + rg * hn);
    float hp = hL[bl * 516 + k];
    float h2 = (1.f - zg) * ng + zg * hp;
    hout[(size_t)b * H_ + k] = h2;
    int s_out = dir ? (S_ - 1 - t) : t;
    enc_bt[((size_t)b * S_ + s_out) * (2 * H_) + dir * H_ + k] = h2;
}

// ---------------------------------------------------------------------------
// hidden = tanh(concat(hf,hb) @ enc_fc_W.T + b)  -> h_dec[0]
// ---------------------------------------------------------------------------
__global__ __launch_bounds__(256)
void enc_fc_kernel(const float* __restrict__ h_enc, const float* __restrict__ W,
                   const float* __restrict__ bias, float* __restrict__ h0)
{
    int b = blockIdx.x, tid = threadIdx.x;
    __shared__ float hc[2 * H_];
    const float* hf = h_enc + (size_t)b * H_;              // dir0, pp0
    const float* hb = h_enc + (size_t)(2 * B_ + b) * H_;   // dir1, pp0
    for (int i = tid; i < H_; i += 256) { hc[i] = hf[i]; hc[H_ + i] = hb[i]; }
    __syncthreads();
    for (int rr = 0; rr < 2; rr++) {
        int i = rr * 256 + tid;
        const float* w = W + (size_t)i * (2 * H_);
        float acc = 0.f;
        for (int j = 0; j < 2 * H_; j += 4) {
            float4 a4 = *(const float4*)&hc[j];
            float4 w4 = *(const float4*)(w + j);
            acc += a4.x * w4.x + a4.y * w4.y + a4.z * w4.z + a4.w * w4.w;
        }
        h0[(size_t)b * H_ + i] = tanhf(acc + bias[i]);
    }
}

// ---------------------------------------------------------------------------
// decoder attention for one step: grid = B_ (one wg per batch row)
// computes scores -> masked softmax -> weighted; writes cat[:,768:1792]
// ---------------------------------------------------------------------------
__global__ __launch_bounds__(256)
void dec_attn_kernel(const float* __restrict__ h_in, const float* __restrict__ attn_W,
                     const float* __restrict__ attn_v, const float* __restrict__ enc_projB,
                     const float* __restrict__ enc_bt, const int* __restrict__ src,
                     float* __restrict__ cat_t)
{
    int b = blockIdx.x, tid = threadIdx.x;
    __shared__ float hL[H_];
    __shared__ float vL[H_];
    __shared__ float hwh[H_];
    __shared__ float aL[S_];
    __shared__ float red[2];
    for (int i = tid; i < H_; i += 256) { hL[i] = h_in[(size_t)b * H_ + i]; vL[i] = attn_v[i]; }
    __syncthreads();
    // hWh = h @ W_h.T (rows of attn_W, cols 0:512)
    for (int rr = 0; rr < 2; rr++) {
        int i = rr * 256 + tid;
        const float* w = attn_W + (size_t)i * G3_;
        float acc = 0.f;
        for (int j = 0; j < H_; j += 4) {
            float4 a4 = *(const float4*)&hL[j];
            float4 w4 = *(const float4*)(w + j);
            acc += a4.x * w4.x + a4.y * w4.y + a4.z * w4.z + a4.w * w4.w;
        }
        hwh[i] = acc;
    }
    __syncthreads();
    // scores[s] = sum_h v[h]*tanh(hwh[h] + enc_projB[b,s,h])  (attn_b folded in)
    int wv = tid >> 6, lane = tid & 63;
    for (int so = 0; so < 32; so++) {
        int s = so * 4 + wv;
        const float* pr = enc_projB + ((size_t)b * S_ + s) * H_;
        float acc = 0.f;
#pragma unroll
        for (int u = 0; u < 8; u++) {
            int hh = u * 64 + lane;
            float x = hwh[hh] + pr[hh];
            float e2 = __expf(2.f * x);
            acc += vL[hh] * (1.f - 2.f / (e2 + 1.f));
        }
#pragma unroll
        for (int off = 1; off < 64; off <<= 1) acc += __shfl_xor(acc, off);
        if (lane == 0) aL[s] = acc;
    }
    __syncthreads();
    // masked softmax over s
    if (tid < S_) {
        float sc = (src[b * S_ + tid] != 0) ? aL[tid] : -1e10f;
        aL[tid] = sc;
    }
    __syncthreads();
    if (tid < 64) {
        float m = fmaxf(aL[tid], aL[tid + 64]);
#pragma unroll
        for (int off = 1; off < 64; off <<= 1) m = fmaxf(m, __shfl_xor(m, off));
        if (tid == 0) red[0] = m;
    }
    __syncthreads();
    if (tid < S_) aL[tid] = expf(aL[tid] - red[0]);
    __syncthreads();
    if (tid < 64) {
        float sv = aL[tid] + aL[tid + 64];
#pragma unroll
        for (int off = 1; off < 64; off <<= 1) sv += __shfl_xor(sv, off);
        if (tid == 0) red[1] = sv;
    }
    __syncthreads();
    if (tid < S_) aL[tid] = aL[tid] / red[1];
    __syncthreads();
    // weighted[d] = sum_s a[s] * enc_bt[b,s,d]; d = tid*4..+3
    const float* eb = enc_bt + (size_t)b * S_ * (2 * H_) + tid * 4;
    float w0 = 0, w1 = 0, w2 = 0, w3 = 0;
    for (int s = 0; s < S_; s++) {
        float a = aL[s];
        float4 v = *(const float4*)(eb + (size_t)s * (2 * H_));
        w0 += a * v.x; w1 += a * v.y; w2 += a * v.z; w3 += a * v.w;
    }
    float4 outv; outv.x = w0; outv.y = w1; outv.z = w2; outv.w = w3;
    *(float4*)(cat_t + (size_t)b * CATK_ + (H_ + E_) + tid * 4) = outv;
}

// ---------------------------------------------------------------------------
// decoder GRU for one step: grid = 64: (b, k-half). writes h_out and cat[:,0:512]
// ---------------------------------------------------------------------------
__global__ __launch_bounds__(256)
void dec_gru_kernel(const float* __restrict__ h_in, float* __restrict__ h_out,
                    const float* __restrict__ Whh, const float* __restrict__ bhh,
                    const float* __restrict__ Wih, const float* __restrict__ gx_emb_t,
                    float* __restrict__ cat_t)
{
    int b = blockIdx.x >> 1;
    int kh = blockIdx.x & 1;
    int tid = threadIdx.x;
    int k = kh * 256 + tid;
    __shared__ float hL[H_];
    __shared__ float wL[2 * H_];
    for (int i = tid; i < H_; i += 256) hL[i] = h_in[(size_t)b * H_ + i];
    const float* wsrc = cat_t + (size_t)b * CATK_ + (H_ + E_);
    for (int i = tid; i < 2 * H_; i += 256) wL[i] = wsrc[i];
    __syncthreads();
    const float* whr = Whh + (size_t)k * H_;
    const float* whz = Whh + (size_t)(H_ + k) * H_;
    const float* whn = Whh + (size_t)(2 * H_ + k) * H_;
    float ar = 0.f, az = 0.f, an = 0.f;
#pragma unroll 4
    for (int j = 0; j < H_; j += 4) {
        float4 h4 = *(const float4*)&hL[j];
        float4 r4 = *(const float4*)(whr + j);
        float4 z4 = *(const float4*)(whz + j);
        float4 n4 = *(const float4*)(whn + j);
        ar += h4.x * r4.x + h4.y * r4.y + h4.z * r4.z + h4.w * r4.w;
        az += h4.x * z4.x + h4.y * z4.y + h4.z * z4.z + h4.w * z4.w;
        an += h4.x * n4.x + h4.y * n4.y + h4.z * n4.z + h4.w * n4.w;
    }
    const float* wir = Wih + (size_t)k * DIN_ + E_;
    const float* wiz = Wih + (size_t)(H_ + k) * DIN_ + E_;
    const float* win = Wih + (size_t)(2 * H_ + k) * DIN_ + E_;
    float br = 0.f, bz = 0.f, bn = 0.f;
#pragma unroll 4
    for (int j = 0; j < 2 * H_; j += 4) {
        float4 w4 = *(const float4*)&wL[j];
        float4 r4 = *(const float4*)(wir + j);
        float4 z4 = *(const float4*)(wiz + j);
        float4 n4 = *(const float4*)(win + j);
        br += w4.x * r4.x + w4.y * r4.y + w4.z * r4.z + w4.w * r4.w;
        bz += w4.x * z4.x + w4.y * z4.y + w4.z * z4.z + w4.w * z4.w;
        bn += w4.x * n4.x + w4.y * n4.y + w4.z * n4.z + w4.w * n4.w;
    }
    const float* gxe = gx_emb_t + (size_t)b * G3_;
    float xr = gxe[k] + br, xz = gxe[H_ + k] + bz, xn = gxe[2 * H_ + k] + bn;
    float hr = ar + bhh[k], hz = az + bhh[H_ + k], hn = an + bhh[2 * H_ + k];
    float rg = 1.f / (1.f + expf(-(xr + hr)));
    float zg = 1.f / (1.f + expf(-(xz + hz)));
    float ng = tanhf(xn + rg * hn);
    float hp = hL[k];
    float h2 = (1.f - zg) * ng + zg * hp;
    h_out[(size_t)b * H_ + k] = h2;
    cat_t[(size_t)b * CATK_ + k] = h2;
}

// ---------------------------------------------------------------------------
// argmax per (t,b) row over V. np tie-break: first (lowest) index.
// ---------------------------------------------------------------------------
__global__ __launch_bounds__(256)
void argmax_kernel(const float* __restrict__ outp, float* __restrict__ preds)
{
    int row = blockIdx.x;          // t*32 + b
    int t = row >> 5, b = row & 31;
    const float* p = outp + ((size_t)b * T_ + t) * V_;
    int tid = threadIdx.x;
    float best = -3.4e38f; int bi = V_;
    for (int i = tid; i < V_; i += 256) {
        float v = p[i];
        if (v > best) { best = v; bi = i; }   // ascending i: strict > keeps first
    }
    __shared__ float bv[256];
    __shared__ int bidx[256];
    bv[tid] = best; bidx[tid] = bi;
    __syncthreads();
    for (int off = 128; off > 0; off >>= 1) {
        if (tid < off) {
            float v2 = bv[tid + off]; int i2 = bidx[tid + off];
            if (v2 > bv[tid] || (v2 == bv[tid] && i2 < bidx[tid])) { bv[tid] = v2; bidx[tid] = i2; }
        }
        __syncthreads();
    }
    if (tid == 0) preds[(size_t)b * T_ + t] = (float)bidx[0];
}

// ---------------------------------------------------------------------------
// zero the t = T-1 slice of outputs and preds
// ---------------------------------------------------------------------------
__global__ __launch_bounds__(256)
void zero_tail_kernel(float* __restrict__ outp, float* __restrict__ preds)
{
    int tid = blockIdx.x * 256 + threadIdx.x;
    if (tid < B_ * V_) {
        int b = tid / V_;
        int c = tid % V_;
        outp[((size_t)b * T_ + (T_ - 1)) * V_ + c] = 0.f;
    }
    if (tid < B_) preds[(size_t)tid * T_ + (T_ - 1)] = 0.f;
}

// ---------------------------------------------------------------------------
extern "C" void kernel_launch(void* const* d_in, const int* in_sizes, int n_in,
                              void* d_out, int out_size, void* d_ws, size_t ws_size,
                              hipStream_t stream)
{
    (void)in_sizes; (void)n_in; (void)out_size; (void)ws_size;
    const int*   src     = (const int*)d_in[0];
    const int*   tgt     = (const int*)d_in[1];
    const float* enc_emb = (const float*)d_in[2];
    const float* Wih_f   = (const float*)d_in[3];
    const float* Whh_f   = (const float*)d_in[4];
    const float* bih_f   = (const float*)d_in[5];
    const float* bhh_f   = (const float*)d_in[6];
    const float* Wih_b   = (const float*)d_in[7];
    const float* Whh_b   = (const float*)d_in[8];
    const float* bih_b   = (const float*)d_in[9];
    const float* bhh_b   = (const float*)d_in[10];
    const float* fcW     = (const float*)d_in[11];
    const float* fcb     = (const float*)d_in[12];
    const float* dec_emb = (const float*)d_in[13];
    const float* attn_W  = (const float*)d_in[14];
    const float* attn_b  = (const float*)d_in[15];
    const float* attn_v  = (const float*)d_in[16];
    const float* dWih    = (const float*)d_in[17];
    const float* dWhh    = (const float*)d_in[18];
    const float* dbih    = (const float*)d_in[19];
    const float* dbhh    = (const float*)d_in[20];
    const float* fc1W    = (const float*)d_in[21];
    const float* fc1b    = (const float*)d_in[22];

    // workspace layout (floats): ~27.3 MB
    float* ws     = (float*)d_ws;
    float* cat    = ws;                       // 63*32*1792 = 3,612,672
    float* gx_emb = cat + (size_t)TD_ * B_ * CATK_;      // 3,096,576
    float* h_enc  = gx_emb + (size_t)TD_ * B_ * G3_;     // [2][2][32][512] = 65,536
    float* h_dec  = h_enc + 2 * 2 * B_ * H_;             // [2][32][512]   = 32,768
    int*   tokf   = (int*)(h_dec + 2 * B_ * H_);         // 4096
    int*   tokb   = tokf + S_ * B_;                      // 4096
    int*   tokd   = tokb + S_ * B_;                      // 2016

    // d_out doubles as phase-local scratch (fully overwritten by fc1 + zero_tail)
    float* dout      = (float*)d_out;
    float* gxf       = dout;                  // [S][B][1536] = 6,291,456
    float* gxb       = dout + (size_t)S_ * B_ * G3_;                // 6,291,456
    float* enc_bt    = dout + (size_t)2 * S_ * B_ * G3_;            // [B][S][1024] = 4,194,304
    float* enc_projB = enc_bt + (size_t)B_ * S_ * 2 * H_;           // [B][S][512]  = 2,097,152
    float* preds     = dout + (size_t)B_ * T_ * V_;                 // output 1

    dim3 thr(256);

    hipLaunchKernelGGL(prep_kernel, dim3(256), thr, 0, stream, src, tgt, tokf, tokb, tokd, h_enc);
    hipLaunchKernelGGL(emb_cat_kernel, dim3(TD_ * B_), thr, 0, stream, tokd, dec_emb, cat);

    // encoder input-gate precompute: gx = emb[src] @ Wih.T + bih  (both dirs)
    hipLaunchKernelGGL((gemm128_kernel<1, 0>), dim3(G3_ / 128, (S_ * B_) / 128), thr, 0, stream,
                       (const float*)nullptr, 0, tokf, enc_emb, Wih_f, E_, bih_f,
                       gxf, G3_, S_ * B_, G3_, E_);
    hipLaunchKernelGGL((gemm128_kernel<1, 0>), dim3(G3_ / 128, (S_ * B_) / 128), thr, 0, stream,
                       (const float*)nullptr, 0, tokb, enc_emb, Wih_b, E_, bih_b,
                       gxb, G3_, S_ * B_, G3_, E_);

    // encoder recurrence (both directions per launch)
    for (int t = 0; t < S_; t++)
        hipLaunchKernelGGL(enc_step_kernel, dim3(128), thr, 0, stream,
                           gxf, gxb, Whh_f, bhh_f, Whh_b, bhh_b, h_enc, enc_bt, t);

    hipLaunchKernelGGL(enc_fc_kernel, dim3(B_), thr, 0, stream, h_enc, fcW, fcb, h_dec);

    // enc_proj = enc_bt @ W_e.T + attn_b   (W_e = attn_W cols 512:1536)
    hipLaunchKernelGGL((gemm128_kernel<0, 0>), dim3(H_ / 128, (B_ * S_) / 128), thr, 0, stream,
                       enc_bt, 2 * H_, (const int*)nullptr, (const float*)nullptr,
                       attn_W + H_, G3_, attn_b, enc_projB, H_, B_ * S_, H_, 2 * H_);

    // decoder embedding gates: gx_emb = dec_emb[tgt] @ dWih[:, :E].T + dbih
    hipLaunchKernelGGL((gemm128_kernel<1, 0>), dim3(G3_ / 128, (TD_ * B_ + 127) / 128), thr, 0, stream,
                       (const float*)nullptr, 0, tokd, dec_emb, dWih, DIN_, dbih,
                       gx_emb, G3_, TD_ * B_, G3_, E_);

    // decoder recurrence
    for (int t = 0; t < TD_; t++) {
        const float* hi = h_dec + (size_t)(t & 1) * B_ * H_;
        float* ho = h_dec + (size_t)(1 - (t & 1)) * B_ * H_;
        float* cat_t = cat + (size_t)t * B_ * CATK_;
        hipLaunchKernelGGL(dec_attn_kernel, dim3(B_), thr, 0, stream,
                           hi, attn_W, attn_v, enc_projB, enc_bt, src, cat_t);
        hipLaunchKernelGGL(dec_gru_kernel, dim3(2 * B_), thr, 0, stream,
                           hi, ho, dWhh, dbhh, dWih, gx_emb + (size_t)t * B_ * G3_, cat_t);
    }

    // the big one: logits = cat @ fc1_W.T + fc1_b  (M=2016, N=32000, K=1792)
    hipLaunchKernelGGL((gemm128_kernel<0, 1>), dim3(V_ / 128, (TD_ * B_ + 127) / 128), thr, 0, stream,
                       cat, CATK_, (const int*)nullptr, (const float*)nullptr,
                       fc1W, CATK_, fc1b, dout, V_, TD_ * B_, V_, CATK_);

    hipLaunchKernelGGL(argmax_kernel, dim3(TD_ * B_), thr, 0, stream, dout, preds);
    hipLaunchKernelGGL(zero_tail_kernel, dim3((B_ * V_ + 255) / 256), thr, 0, stream, dout, preds);
}

// Round 2
// 16947.322 us; speedup vs baseline: 1.1292x; 1.1292x over previous
//
#include <hip/hip_runtime.h>

#define V_ 32000
#define E_ 256
#define H_ 512
#define B_ 32
#define S_ 128
#define T_ 64
#define TD_ 63        // decoder steps (T-1)
#define G3_ 1536      // 3*H
#define CATK_ 1792    // H + E + 2H
#define DIN_ 1280     // E + 2H
#define MPAD_ 2048    // padded M for fc1 MFMA

typedef __attribute__((ext_vector_type(8))) short bf16x8;
typedef __attribute__((ext_vector_type(4))) float f32x4;

__device__ inline unsigned short bf16_rne(float x) {
    unsigned u = __float_as_uint(x);
    unsigned r = u + 0x7FFFu + ((u >> 16) & 1u);
    return (unsigned short)(r >> 16);
}

// ---------------------------------------------------------------------------
// prep: token permutations + zero encoder hidden state
// ---------------------------------------------------------------------------
__global__ __launch_bounds__(256)
void prep_kernel(const int* __restrict__ src, const int* __restrict__ tgt,
                 int* __restrict__ tokf, int* __restrict__ tokb, int* __restrict__ tokd,
                 float* __restrict__ h_enc)
{
    int tid = blockIdx.x * 256 + threadIdx.x;
    if (tid < S_ * B_) {
        int s = tid >> 5, b = tid & 31;
        tokf[tid] = src[b * S_ + s];
        tokb[tid] = src[b * S_ + (S_ - 1 - s)];
    }
    if (tid < TD_ * B_) {
        int t = tid >> 5, b = tid & 31;
        tokd[tid] = tgt[b * T_ + t];
    }
    if (tid < 2 * 2 * B_ * H_) h_enc[tid] = 0.f;   // [dir][pp][B][H]
}

// ---------------------------------------------------------------------------
// write decoder embeddings into cat[:, 512:768]
// ---------------------------------------------------------------------------
__global__ __launch_bounds__(256)
void emb_cat_kernel(const int* __restrict__ tokd, const float* __restrict__ dec_emb,
                    float* __restrict__ cat)
{
    int row = blockIdx.x;          // row = t*32 + b
    int tid = threadIdx.x;         // 0..255 == E_
    cat[(size_t)row * CATK_ + H_ + tid] = dec_emb[(size_t)tokd[row] * E_ + tid];
}

// ---------------------------------------------------------------------------
// Generic fp32 GEMM (used for small GEMMs + fallback fc1)
// ---------------------------------------------------------------------------
template<int GATHER, int FC1MAP>
__global__ __launch_bounds__(256)
void gemm128_kernel(const float* __restrict__ A, int lda,
                    const int* __restrict__ tokens, const float* __restrict__ emb,
                    const float* __restrict__ W, int ldw,
                    const float* __restrict__ bias,
                    float* __restrict__ C, int ldc,
                    int M, int N, int K)
{
    __shared__ float As[16][132];
    __shared__ float Ws[16][132];
    (void)N;
    int tid = threadIdx.x;
    int m0 = blockIdx.y * 128, n0 = blockIdx.x * 128;
    int tx = tid & 15, ty = tid >> 4;
    float c[8][8];
#pragma unroll
    for (int i = 0; i < 8; i++)
#pragma unroll
        for (int j = 0; j < 8; j++) c[i][j] = 0.f;

    int arow = tid >> 1;
    int kq = (tid & 1) * 8;

    int am = m0 + arow; if (am >= M) am = M - 1;
    const float* arp;
    if (GATHER) arp = emb + (size_t)tokens[am] * (size_t)K;
    else        arp = A + (size_t)am * (size_t)lda;
    const float* wrp = W + (size_t)(n0 + arow) * (size_t)ldw;

    for (int kb = 0; kb < K; kb += 16) {
        __syncthreads();
        float4 a0 = *(const float4*)(arp + kb + kq);
        float4 a1 = *(const float4*)(arp + kb + kq + 4);
        float4 w0 = *(const float4*)(wrp + kb + kq);
        float4 w1 = *(const float4*)(wrp + kb + kq + 4);
        As[kq + 0][arow] = a0.x; As[kq + 1][arow] = a0.y;
        As[kq + 2][arow] = a0.z; As[kq + 3][arow] = a0.w;
        As[kq + 4][arow] = a1.x; As[kq + 5][arow] = a1.y;
        As[kq + 6][arow] = a1.z; As[kq + 7][arow] = a1.w;
        Ws[kq + 0][arow] = w0.x; Ws[kq + 1][arow] = w0.y;
        Ws[kq + 2][arow] = w0.z; Ws[kq + 3][arow] = w0.w;
        Ws[kq + 4][arow] = w1.x; Ws[kq + 5][arow] = w1.y;
        Ws[kq + 6][arow] = w1.z; Ws[kq + 7][arow] = w1.w;
        __syncthreads();
#pragma unroll
        for (int kk = 0; kk < 16; kk++) {
            float a[8], bb[8];
            *(float4*)&a[0]  = *(const float4*)&As[kk][ty * 8];
            *(float4*)&a[4]  = *(const float4*)&As[kk][ty * 8 + 4];
            *(float4*)&bb[0] = *(const float4*)&Ws[kk][tx * 8];
            *(float4*)&bb[4] = *(const float4*)&Ws[kk][tx * 8 + 4];
#pragma unroll
            for (int i = 0; i < 8; i++)
#pragma unroll
                for (int j = 0; j < 8; j++) c[i][j] += a[i] * bb[j];
        }
    }

#pragma unroll
    for (int i = 0; i < 8; i++) {
        int m = m0 + ty * 8 + i;
        if (m < M) {
            size_t rowoff;
            if (FC1MAP) { int tt = m >> 5, bb2 = m & 31; rowoff = ((size_t)bb2 * T_ + tt) * (size_t)ldc; }
            else        rowoff = (size_t)m * (size_t)ldc;
#pragma unroll
            for (int j = 0; j < 8; j += 4) {
                int n = n0 + tx * 8 + j;
                float4 v;
                v.x = c[i][j + 0] + bias[n + 0];
                v.y = c[i][j + 1] + bias[n + 1];
                v.z = c[i][j + 2] + bias[n + 2];
                v.w = c[i][j + 3] + bias[n + 3];
                *(float4*)(C + rowoff + n) = v;
            }
        }
    }
}

// ---------------------------------------------------------------------------
// split cat (fp32 [2016][1792]) into bf16 hi/lo, padded to 2048 rows (zeros)
// ---------------------------------------------------------------------------
__global__ __launch_bounds__(256)
void splitA_kernel(const float* __restrict__ cat,
                   unsigned short* __restrict__ Ahi, unsigned short* __restrict__ Alo)
{
    size_t i4 = ((size_t)blockIdx.x * 256 + threadIdx.x) * 4;
    if (i4 >= (size_t)MPAD_ * CATK_) return;
    size_t row = i4 / CATK_;
    float4 v;
    if (row < (size_t)TD_ * B_) v = *(const float4*)(cat + i4);
    else { v.x = v.y = v.z = v.w = 0.f; }
    float f[4] = {v.x, v.y, v.z, v.w};
    unsigned short h[4], l[4];
#pragma unroll
    for (int j = 0; j < 4; j++) {
        h[j] = bf16_rne(f[j]);
        float hf = __uint_as_float((unsigned)h[j] << 16);
        l[j] = bf16_rne(f[j] - hf);
    }
    *(ushort4*)(Ahi + i4) = make_ushort4(h[0], h[1], h[2], h[3]);
    *(ushort4*)(Alo + i4) = make_ushort4(l[0], l[1], l[2], l[3]);
}

// ---------------------------------------------------------------------------
// fc1 via split-bf16 MFMA, 3 products (hh + hl + lh) == fp32-accurate logits.
// C[m=t*32+b][n] = sum_k cat[m][k]*W[n][k] + bias[n], stored at row b*T+t.
// 128x128 tile, BK=32, 4 waves (2x2 of 64x64). W split done on the fly.
// grid = (M/128 = 16, N/128 = 250): m-major linear order -> W panel L2 reuse.
// ---------------------------------------------------------------------------
__global__ __launch_bounds__(256)
void fc1_mfma_kernel(const unsigned short* __restrict__ Ahi,
                     const unsigned short* __restrict__ Alo,
                     const float* __restrict__ W,
                     const float* __restrict__ bias,
                     float* __restrict__ C)
{
    __shared__ unsigned short lA[2][128][40];   // [hi/lo][row][k], stride 40 (80B)
    __shared__ unsigned short lW[2][128][40];
    const int tid = threadIdx.x;
    const int m0 = blockIdx.x * 128, n0 = blockIdx.y * 128;
    const int w = tid >> 6, lane = tid & 63;
    const int wm = w >> 1, wn = w & 1;
    const int frow = lane & 15, fk = (lane >> 4) * 8;

    f32x4 acc[4][4];
#pragma unroll
    for (int mi = 0; mi < 4; mi++)
#pragma unroll
        for (int ni = 0; ni < 4; ni++) acc[mi][ni] = (f32x4){0.f, 0.f, 0.f, 0.f};

    const int srow = tid >> 1;          // 0..127
    const int skq = (tid & 1) * 16;     // 0 or 16

    const unsigned short* gAhi = Ahi + (size_t)(m0 + srow) * CATK_ + skq;
    const unsigned short* gAlo = Alo + (size_t)(m0 + srow) * CATK_ + skq;
    const float*          gW   = W   + (size_t)(n0 + srow) * CATK_ + skq;

    int4 rAh0, rAh1, rAl0, rAl1;
    float4 rW0, rW1, rW2, rW3;

#define FC1_LOAD(kb)                                        \
    do {                                                    \
        rAh0 = *(const int4*)(gAhi + (kb));                 \
        rAh1 = *(const int4*)(gAhi + (kb) + 8);             \
        rAl0 = *(const int4*)(gAlo + (kb));                 \
        rAl1 = *(const int4*)(gAlo + (kb) + 8);             \
        rW0  = *(const float4*)(gW + (kb));                 \
        rW1  = *(const float4*)(gW + (kb) + 4);             \
        rW2  = *(const float4*)(gW + (kb) + 8);             \
        rW3  = *(const float4*)(gW + (kb) + 12);            \
    } while (0)

    FC1_LOAD(0);

    for (int kb = 0; kb < CATK_; kb += 32) {
        __syncthreads();   // previous iter's LDS reads complete
        // stage A (already split)
        *(int4*)&lA[0][srow][skq]     = rAh0;
        *(int4*)&lA[0][srow][skq + 8] = rAh1;
        *(int4*)&lA[1][srow][skq]     = rAl0;
        *(int4*)&lA[1][srow][skq + 8] = rAl1;
        // convert + stage W
        {
            float f[16] = {rW0.x, rW0.y, rW0.z, rW0.w, rW1.x, rW1.y, rW1.z, rW1.w,
                           rW2.x, rW2.y, rW2.z, rW2.w, rW3.x, rW3.y, rW3.z, rW3.w};
            unsigned hp[8], lp[8];
#pragma unroll
            for (int j = 0; j < 8; j++) {
                float x0 = f[2 * j], x1 = f[2 * j + 1];
                unsigned short h0 = bf16_rne(x0), h1 = bf16_rne(x1);
                float r0 = x0 - __uint_as_float((unsigned)h0 << 16);
                float r1 = x1 - __uint_as_float((unsigned)h1 << 16);
                hp[j] = (unsigned)h0 | ((unsigned)h1 << 16);
                lp[j] = (unsigned)bf16_rne(r0) | ((unsigned)bf16_rne(r1) << 16);
            }
            *(int4*)&lW[0][srow][skq]     = make_int4(hp[0], hp[1], hp[2], hp[3]);
            *(int4*)&lW[0][srow][skq + 8] = make_int4(hp[4], hp[5], hp[6], hp[7]);
            *(int4*)&lW[1][srow][skq]     = make_int4(lp[0], lp[1], lp[2], lp[3]);
            *(int4*)&lW[1][srow][skq + 8] = make_int4(lp[4], lp[5], lp[6], lp[7]);
        }
        __syncthreads();
        if (kb + 32 < CATK_) FC1_LOAD(kb + 32);   // issue next-tile loads early

        bf16x8 a[2][4];
#pragma unroll
        for (int mi = 0; mi < 4; mi++) {
            int r = wm * 64 + mi * 16 + frow;
            a[0][mi] = *(const bf16x8*)&lA[0][r][fk];
            a[1][mi] = *(const bf16x8*)&lA[1][r][fk];
        }
#pragma unroll
        for (int ni = 0; ni < 4; ni++) {
            int r = wn * 64 + ni * 16 + frow;
            bf16x8 bh = *(const bf16x8*)&lW[0][r][fk];
            bf16x8 bl = *(const bf16x8*)&lW[1][r][fk];
#pragma unroll
            for (int mi = 0; mi < 4; mi++) {
                acc[mi][ni] = __builtin_amdgcn_mfma_f32_16x16x32_bf16(a[0][mi], bh, acc[mi][ni], 0, 0, 0);
                acc[mi][ni] = __builtin_amdgcn_mfma_f32_16x16x32_bf16(a[1][mi], bh, acc[mi][ni], 0, 0, 0);
                acc[mi][ni] = __builtin_amdgcn_mfma_f32_16x16x32_bf16(a[0][mi], bl, acc[mi][ni], 0, 0, 0);
            }
        }
    }
#undef FC1_LOAD

    // epilogue: C/D layout col=lane&15, row=(lane>>4)*4+reg  [m89-verified]
#pragma unroll
    for (int ni = 0; ni < 4; ni++) {
        int col = n0 + wn * 64 + ni * 16 + frow;
        float bc = bias[col];
#pragma unroll
        for (int mi = 0; mi < 4; mi++) {
            int mbase = m0 + wm * 64 + mi * 16 + (lane >> 4) * 4;
            f32x4 v = acc[mi][ni];
#pragma unroll
            for (int r = 0; r < 4; r++) {
                int m = mbase + r;
                if (m < TD_ * B_) {
                    int tt = m >> 5, bb2 = m & 31;
                    C[((size_t)bb2 * T_ + tt) * V_ + col] = v[r] + bc;
                }
            }
        }
    }
}

// ---------------------------------------------------------------------------
// one bi-GRU encoder step (both directions). grid = 128
// ---------------------------------------------------------------------------
__global__ __launch_bounds__(256)
void enc_step_kernel(const float* __restrict__ gxf, const float* __restrict__ gxb,
                     const float* __restrict__ Whh_f, const float* __restrict__ bhh_f,
                     const float* __restrict__ Whh_b, const float* __restrict__ bhh_b,
                     float* __restrict__ h_enc, float* __restrict__ enc_bt, int t)
{
    int bx = blockIdx.x;
    int dir = bx >> 6;
    int bh  = (bx >> 5) & 1;
    int kc  = bx & 31;
    int tid = threadIdx.x;
    int bl = tid & 15;
    int kl = tid >> 4;
    int b = bh * 16 + bl;
    int k = kc * 16 + kl;
    const float* Whh = dir ? Whh_b : Whh_f;
    const float* bhh = dir ? bhh_b : bhh_f;
    const float* gx  = dir ? gxb : gxf;
    int pp = t & 1;
    const float* hin  = h_enc + (size_t)(dir * 2 + pp) * B_ * H_;
    float* hout = h_enc + (size_t)(dir * 2 + (1 - pp)) * B_ * H_;

    __shared__ float hL[16 * 516];
    {
        const float* hsrc = hin + (size_t)bh * 16 * H_;
        for (int i = tid * 4; i < 16 * H_; i += 1024) {
            int r = i >> 9;
            int cix = i & (H_ - 1);
            float4 v = *(const float4*)(hsrc + i);
            *(float4*)&hL[r * 516 + cix] = v;
        }
    }
    __syncthreads();

    const float* wr = Whh + (size_t)k * H_;
    const float* wz = Whh + (size_t)(H_ + k) * H_;
    const float* wn = Whh + (size_t)(2 * H_ + k) * H_;
    const float* hv = &hL[bl * 516];
    float ar = 0.f, az = 0.f, an = 0.f;
#pragma unroll 4
    for (int j = 0; j < H_; j += 4) {
        float4 h4 = *(const float4*)(hv + j);
        float4 r4 = *(const float4*)(wr + j);
        float4 z4 = *(const float4*)(wz + j);
        float4 n4 = *(const float4*)(wn + j);
        ar += h4.x * r4.x + h4.y * r4.y + h4.z * r4.z + h4.w * r4.w;
        az += h4.x * z4.x + h4.y * z4.y + h4.z * z4.z + h4.w * z4.w;
        an += h4.x * n4.x + h4.y * n4.y + h4.z * n4.z + h4.w * n4.w;
    }
    const float* gxr = gx + ((size_t)t * B_ + b) * G3_;
    float xr = gxr[k], xz = gxr[H_ + k], xn = gxr[2 * H_ + k];
    float hr = ar + bhh[k], hz = az + bhh[H_ + k], hn = an + bhh[2 * H_ + k];
    float rg = 1.f / (1.f + expf(-(xr + hr)));
    float zg = 1.f / (1.f + expf(-(xz + hz)));
    float ng = tanhf(xn + rg * hn);
    float hp = hL[bl * 516 + k];
    float h2 = (1.f - zg) * ng + zg * hp;
    hout[(size_t)b * H_ + k] = h2;
    int s_out = dir ? (S_ - 1 - t) : t;
    enc_bt[((size_t)b * S_ + s_out) * (2 * H_) + dir * H_ + k] = h2;
}

// ---------------------------------------------------------------------------
__global__ __launch_bounds__(256)
void enc_fc_kernel(const float* __restrict__ h_enc, const float* __restrict__ W,
                   const float* __restrict__ bias, float* __restrict__ h0)
{
    int b = blockIdx.x, tid = threadIdx.x;
    __shared__ float hc[2 * H_];
    const float* hf = h_enc + (size_t)b * H_;
    const float* hb = h_enc + (size_t)(2 * B_ + b) * H_;
    for (int i = tid; i < H_; i += 256) { hc[i] = hf[i]; hc[H_ + i] = hb[i]; }
    __syncthreads();
    for (int rr = 0; rr < 2; rr++) {
        int i = rr * 256 + tid;
        const float* w = W + (size_t)i * (2 * H_);
        float acc = 0.f;
        for (int j = 0; j < 2 * H_; j += 4) {
            float4 a4 = *(const float4*)&hc[j];
            float4 w4 = *(const float4*)(w + j);
            acc += a4.x * w4.x + a4.y * w4.y + a4.z * w4.z + a4.w * w4.w;
        }
        h0[(size_t)b * H_ + i] = tanhf(acc + bias[i]);
    }
}

// ---------------------------------------------------------------------------
__global__ __launch_bounds__(256)
void dec_attn_kernel(const float* __restrict__ h_in, const float* __restrict__ attn_W,
                     const float* __restrict__ attn_v, const float* __restrict__ enc_projB,
                     const float* __restrict__ enc_bt, const int* __restrict__ src,
                     float* __restrict__ cat_t)
{
    int b = blockIdx.x, tid = threadIdx.x;
    __shared__ float hL[H_];
    __shared__ float vL[H_];
    __shared__ float hwh[H_];
    __shared__ float aL[S_];
    __shared__ float red[2];
    for (int i = tid; i < H_; i += 256) { hL[i] = h_in[(size_t)b * H_ + i]; vL[i] = attn_v[i]; }
    __syncthreads();
    for (int rr = 0; rr < 2; rr++) {
        int i = rr * 256 + tid;
        const float* w = attn_W + (size_t)i * G3_;
        float acc = 0.f;
        for (int j = 0; j < H_; j += 4) {
            float4 a4 = *(const float4*)&hL[j];
            float4 w4 = *(const float4*)(w + j);
            acc += a4.x * w4.x + a4.y * w4.y + a4.z * w4.z + a4.w * w4.w;
        }
        hwh[i] = acc;
    }
    __syncthreads();
    int wv = tid >> 6, lane = tid & 63;
    for (int so = 0; so < 32; so++) {
        int s = so * 4 + wv;
        const float* pr = enc_projB + ((size_t)b * S_ + s) * H_;
        float acc = 0.f;
#pragma unroll
        for (int u = 0; u < 8; u++) {
            int hh = u * 64 + lane;
            float x = hwh[hh] + pr[hh];
            float e2 = __expf(2.f * x);
            acc += vL[hh] * (1.f - 2.f / (e2 + 1.f));
        }
#pragma unroll
        for (int off = 1; off < 64; off <<= 1) acc += __shfl_xor(acc, off);
        if (lane == 0) aL[s] = acc;
    }
    __syncthreads();
    if (tid < S_) {
        float sc = (src[b * S_ + tid] != 0) ? aL[tid] : -1e10f;
        aL[tid] = sc;
    }
    __syncthreads();
    if (tid < 64) {
        float m = fmaxf(aL[tid], aL[tid + 64]);
#pragma unroll
        for (int off = 1; off < 64; off <<= 1) m = fmaxf(m, __shfl_xor(m, off));
        if (tid == 0) red[0] = m;
    }
    __syncthreads();
    if (tid < S_) aL[tid] = expf(aL[tid] - red[0]);
    __syncthreads();
    if (tid < 64) {
        float sv = aL[tid] + aL[tid + 64];
#pragma unroll
        for (int off = 1; off < 64; off <<= 1) sv += __shfl_xor(sv, off);
        if (tid == 0) red[1] = sv;
    }
    __syncthreads();
    if (tid < S_) aL[tid] = aL[tid] / red[1];
    __syncthreads();
    const float* eb = enc_bt + (size_t)b * S_ * (2 * H_) + tid * 4;
    float w0 = 0, w1 = 0, w2 = 0, w3 = 0;
    for (int s = 0; s < S_; s++) {
        float a = aL[s];
        float4 v = *(const float4*)(eb + (size_t)s * (2 * H_));
        w0 += a * v.x; w1 += a * v.y; w2 += a * v.z; w3 += a * v.w;
    }
    float4 outv; outv.x = w0; outv.y = w1; outv.z = w2; outv.w = w3;
    *(float4*)(cat_t + (size_t)b * CATK_ + (H_ + E_) + tid * 4) = outv;
}

// ---------------------------------------------------------------------------
__global__ __launch_bounds__(256)
void dec_gru_kernel(const float* __restrict__ h_in, float* __restrict__ h_out,
                    const float* __restrict__ Whh, const float* __restrict__ bhh,
                    const float* __restrict__ Wih, const float* __restrict__ gx_emb_t,
                    float* __restrict__ cat_t)
{
    int b = blockIdx.x >> 1;
    int kh = blockIdx.x & 1;
    int tid = threadIdx.x;
    int k = kh * 256 + tid;
    __shared__ float hL[H_];
    __shared__ float wL[2 * H_];
    for (int i = tid; i < H_; i += 256) hL[i] = h_in[(size_t)b * H_ + i];
    const float* wsrc = cat_t + (size_t)b * CATK_ + (H_ + E_);
    for (int i = tid; i < 2 * H_; i += 256) wL[i] = wsrc[i];
    __syncthreads();
    const float* whr = Whh + (size_t)k * H_;
    const float* whz = Whh + (size_t)(H_ + k) * H_;
    const float* whn = Whh + (size_t)(2 * H_ + k) * H_;
    float ar = 0.f, az = 0.f, an = 0.f;
#pragma unroll 4
    for (int j = 0; j < H_; j += 4) {
        float4 h4 = *(const float4*)&hL[j];
        float4 r4 = *(const float4*)(whr + j);
        float4 z4 = *(const float4*)(whz + j);
        float4 n4 = *(const float4*)(whn + j);
        ar += h4.x * r4.x + h4.y * r4.y + h4.z * r4.z + h4.w * r4.w;
        az += h4.x * z4.x + h4.y * z4.y + h4.z * z4.z + h4.w * z4.w;
        an += h4.x * n4.x + h4.y * n4.y + h4.z * n4.z + h4.w * n4.w;
    }
    const float* wir = Wih + (size_t)k * DIN_ + E_;
    const float* wiz = Wih + (size_t)(H_ + k) * DIN_ + E_;
    const float* win = Wih + (size_t)(2 * H_ + k) * DIN_ + E_;
    float br = 0.f, bz = 0.f, bn = 0.f;
#pragma unroll 4
    for (int j = 0; j < 2 * H_; j += 4) {
        float4 w4 = *(const float4*)&wL[j];
        float4 r4 = *(const float4*)(wir + j);
        float4 z4 = *(const float4*)(wiz + j);
        float4 n4 = *(const float4*)(win + j);
        br += w4.x * r4.x + w4.y * r4.y + w4.z * r4.z + w4.w * r4.w;
        bz += w4.x * z4.x + w4.y * z4.y + w4.z * z4.z + w4.w * z4.w;
        bn += w4.x * n4.x + w4.y * n4.y + w4.z * n4.z + w4.w * n4.w;
    }
    const float* gxe = gx_emb_t + (size_t)b * G3_;
    float xr = gxe[k] + br, xz = gxe[H_ + k] + bz, xn = gxe[2 * H_ + k] + bn;
    float hr = ar + bhh[k], hz = az + bhh[H_ + k], hn = an + bhh[2 * H_ + k];
    float rg = 1.f / (1.f + expf(-(xr + hr)));
    float zg = 1.f / (1.f + expf(-(xz + hz)));
    float ng = tanhf(xn + rg * hn);
    float hp = hL[k];
    float h2 = (1.f - zg) * ng + zg * hp;
    h_out[(size_t)b * H_ + k] = h2;
    cat_t[(size_t)b * CATK_ + k] = h2;
}

// ---------------------------------------------------------------------------
__global__ __launch_bounds__(256)
void argmax_kernel(const float* __restrict__ outp, float* __restrict__ preds)
{
    int row = blockIdx.x;
    int t = row >> 5, b = row & 31;
    const float* p = outp + ((size_t)b * T_ + t) * V_;
    int tid = threadIdx.x;
    float best = -3.4e38f; int bi = V_;
    for (int i = tid; i < V_; i += 256) {
        float v = p[i];
        if (v > best) { best = v; bi = i; }
    }
    __shared__ float bv[256];
    __shared__ int bidx[256];
    bv[tid] = best; bidx[tid] = bi;
    __syncthreads();
    for (int off = 128; off > 0; off >>= 1) {
        if (tid < off) {
            float v2 = bv[tid + off]; int i2 = bidx[tid + off];
            if (v2 > bv[tid] || (v2 == bv[tid] && i2 < bidx[tid])) { bv[tid] = v2; bidx[tid] = i2; }
        }
        __syncthreads();
    }
    if (tid == 0) preds[(size_t)b * T_ + t] = (float)bidx[0];
}

// ---------------------------------------------------------------------------
__global__ __launch_bounds__(256)
void zero_tail_kernel(float* __restrict__ outp, float* __restrict__ preds)
{
    int tid = blockIdx.x * 256 + threadIdx.x;
    if (tid < B_ * V_) {
        int b = tid / V_;
        int c = tid % V_;
        outp[((size_t)b * T_ + (T_ - 1)) * V_ + c] = 0.f;
    }
    if (tid < B_) preds[(size_t)tid * T_ + (T_ - 1)] = 0.f;
}

// ---------------------------------------------------------------------------
extern "C" void kernel_launch(void* const* d_in, const int* in_sizes, int n_in,
                              void* d_out, int out_size, void* d_ws, size_t ws_size,
                              hipStream_t stream)
{
    (void)in_sizes; (void)n_in; (void)out_size;
    const int*   src     = (const int*)d_in[0];
    const int*   tgt     = (const int*)d_in[1];
    const float* enc_emb = (const float*)d_in[2];
    const float* Wih_f   = (const float*)d_in[3];
    const float* Whh_f   = (const float*)d_in[4];
    const float* bih_f   = (const float*)d_in[5];
    const float* bhh_f   = (const float*)d_in[6];
    const float* Wih_b   = (const float*)d_in[7];
    const float* Whh_b   = (const float*)d_in[8];
    const float* bih_b   = (const float*)d_in[9];
    const float* bhh_b   = (const float*)d_in[10];
    const float* fcW     = (const float*)d_in[11];
    const float* fcb     = (const float*)d_in[12];
    const float* dec_emb = (const float*)d_in[13];
    const float* attn_W  = (const float*)d_in[14];
    const float* attn_b  = (const float*)d_in[15];
    const float* attn_v  = (const float*)d_in[16];
    const float* dWih    = (const float*)d_in[17];
    const float* dWhh    = (const float*)d_in[18];
    const float* dbih    = (const float*)d_in[19];
    const float* dbhh    = (const float*)d_in[20];
    const float* fc1W    = (const float*)d_in[21];
    const float* fc1b    = (const float*)d_in[22];

    // workspace layout
    float* ws     = (float*)d_ws;
    float* cat    = ws;                                  // 3,612,672 f
    float* gx_emb = cat + (size_t)TD_ * B_ * CATK_;      // 3,096,576 f
    float* h_enc  = gx_emb + (size_t)TD_ * B_ * G3_;     // 65,536 f
    float* h_dec  = h_enc + 2 * 2 * B_ * H_;             // 32,768 f
    int*   tokf   = (int*)(h_dec + 2 * B_ * H_);         // 4096 i
    int*   tokb   = tokf + S_ * B_;                      // 4096 i
    int*   tokd   = tokb + S_ * B_;                      // pad to 4096 i
    unsigned short* Ahi = (unsigned short*)(tokd + 4096);
    unsigned short* Alo = Ahi + (size_t)MPAD_ * CATK_;
    size_t ws_req = (size_t)((char*)(Alo + (size_t)MPAD_ * CATK_) - (char*)d_ws);
    const bool use_mfma = (ws_size >= ws_req);

    // d_out doubles as phase-local scratch (fully overwritten later)
    float* dout      = (float*)d_out;
    float* gxf       = dout;
    float* gxb       = dout + (size_t)S_ * B_ * G3_;
    float* enc_bt    = dout + (size_t)2 * S_ * B_ * G3_;
    float* enc_projB = enc_bt + (size_t)B_ * S_ * 2 * H_;
    float* preds     = dout + (size_t)B_ * T_ * V_;

    dim3 thr(256);

    hipLaunchKernelGGL(prep_kernel, dim3(256), thr, 0, stream, src, tgt, tokf, tokb, tokd, h_enc);
    hipLaunchKernelGGL(emb_cat_kernel, dim3(TD_ * B_), thr, 0, stream, tokd, dec_emb, cat);

    hipLaunchKernelGGL((gemm128_kernel<1, 0>), dim3(G3_ / 128, (S_ * B_) / 128), thr, 0, stream,
                       (const float*)nullptr, 0, tokf, enc_emb, Wih_f, E_, bih_f,
                       gxf, G3_, S_ * B_, G3_, E_);
    hipLaunchKernelGGL((gemm128_kernel<1, 0>), dim3(G3_ / 128, (S_ * B_) / 128), thr, 0, stream,
                       (const float*)nullptr, 0, tokb, enc_emb, Wih_b, E_, bih_b,
                       gxb, G3_, S_ * B_, G3_, E_);

    for (int t = 0; t < S_; t++)
        hipLaunchKernelGGL(enc_step_kernel, dim3(128), thr, 0, stream,
                           gxf, gxb, Whh_f, bhh_f, Whh_b, bhh_b, h_enc, enc_bt, t);

    hipLaunchKernelGGL(enc_fc_kernel, dim3(B_), thr, 0, stream, h_enc, fcW, fcb, h_dec);

    hipLaunchKernelGGL((gemm128_kernel<0, 0>), dim3(H_ / 128, (B_ * S_) / 128), thr, 0, stream,
                       enc_bt, 2 * H_, (const int*)nullptr, (const float*)nullptr,
                       attn_W + H_, G3_, attn_b, enc_projB, H_, B_ * S_, H_, 2 * H_);

    hipLaunchKernelGGL((gemm128_kernel<1, 0>), dim3(G3_ / 128, (TD_ * B_ + 127) / 128), thr, 0, stream,
                       (const float*)nullptr, 0, tokd, dec_emb, dWih, DIN_, dbih,
                       gx_emb, G3_, TD_ * B_, G3_, E_);

    for (int t = 0; t < TD_; t++) {
        const float* hi = h_dec + (size_t)(t & 1) * B_ * H_;
        float* ho = h_dec + (size_t)(1 - (t & 1)) * B_ * H_;
        float* cat_t = cat + (size_t)t * B_ * CATK_;
        hipLaunchKernelGGL(dec_attn_kernel, dim3(B_), thr, 0, stream,
                           hi, attn_W, attn_v, enc_projB, enc_bt, src, cat_t);
        hipLaunchKernelGGL(dec_gru_kernel, dim3(2 * B_), thr, 0, stream,
                           hi, ho, dWhh, dbhh, dWih, gx_emb + (size_t)t * B_ * G3_, cat_t);
    }

    if (use_mfma) {
        hipLaunchKernelGGL(splitA_kernel, dim3((MPAD_ * CATK_ / 4 + 255) / 256), thr, 0, stream,
                           cat, Ahi, Alo);
        hipLaunchKernelGGL(fc1_mfma_kernel, dim3(MPAD_ / 128, V_ / 128), thr, 0, stream,
                           Ahi, Alo, fc1W, fc1b, dout);
    } else {
        hipLaunchKernelGGL((gemm128_kernel<0, 1>), dim3(V_ / 128, (TD_ * B_ + 127) / 128), thr, 0, stream,
                           cat, CATK_, (const int*)nullptr, (const float*)nullptr,
                           fc1W, CATK_, fc1b, dout, V_, TD_ * B_, V_, CATK_);
    }

    hipLaunchKernelGGL(argmax_kernel, dim3(TD_ * B_), thr, 0, stream, dout, preds);
    hipLaunchKernelGGL(zero_tail_kernel, dim3((B_ * V_ + 255) / 256), thr, 0, stream, dout, preds);
}

// Round 3
// 15996.204 us; speedup vs baseline: 1.1963x; 1.0595x over previous
//
#include <hip/hip_runtime.h>

#define V_ 32000
#define E_ 256
#define H_ 512
#define B_ 32
#define S_ 128
#define T_ 64
#define TD_ 63        // decoder steps (T-1)
#define G3_ 1536      // 3*H
#define CATK_ 1792    // H + E + 2H
#define DIN_ 1280     // E + 2H
#define MPAD_ 2048    // padded M for fc1 MFMA

typedef __attribute__((ext_vector_type(8))) short bf16x8;
typedef __attribute__((ext_vector_type(4))) float f32x4;

__device__ inline unsigned short bf16_rne(float x) {
    unsigned u = __float_as_uint(x);
    unsigned r = u + 0x7FFFu + ((u >> 16) & 1u);
    return (unsigned short)(r >> 16);
}

// 4-grouped transposed index for h/weighted vectors: element j of batch b
#define IDX4(j, b) (((size_t)((j) >> 2) * (B_ * 4)) + (b) * 4 + ((j) & 3))

// ---------------------------------------------------------------------------
// device-scope sense-reversing grid barrier (all blocks co-resident: grid=128
// blocks of 256 thr on 256 CUs -> dispatch fills immediately, no occupancy edge)
// ---------------------------------------------------------------------------
__device__ __forceinline__ void grid_bar(unsigned* cnt, unsigned* gen, unsigned nb)
{
    __syncthreads();
    if (threadIdx.x == 0) {
        __threadfence();   // flush this block's writes to device coherence point
        unsigned g = __hip_atomic_load(gen, __ATOMIC_RELAXED, __HIP_MEMORY_SCOPE_AGENT);
        unsigned a = __hip_atomic_fetch_add(cnt, 1u, __ATOMIC_ACQ_REL, __HIP_MEMORY_SCOPE_AGENT);
        if (a == nb - 1u) {
            __hip_atomic_store(cnt, 0u, __ATOMIC_RELAXED, __HIP_MEMORY_SCOPE_AGENT);
            __hip_atomic_store(gen, g + 1u, __ATOMIC_RELEASE, __HIP_MEMORY_SCOPE_AGENT);
        } else {
            while (__hip_atomic_load(gen, __ATOMIC_ACQUIRE, __HIP_MEMORY_SCOPE_AGENT) == g)
                __builtin_amdgcn_s_sleep(2);
        }
    }
    __syncthreads();
}

// ---------------------------------------------------------------------------
// prep: token permutations + zero encoder hidden state + zero barrier counters
// ---------------------------------------------------------------------------
__global__ __launch_bounds__(256)
void prep_kernel(const int* __restrict__ src, const int* __restrict__ tgt,
                 int* __restrict__ tokf, int* __restrict__ tokb, int* __restrict__ tokd,
                 float* __restrict__ h_enc, unsigned* __restrict__ bars)
{
    int tid = blockIdx.x * 256 + threadIdx.x;
    if (tid < S_ * B_) {
        int s = tid >> 5, b = tid & 31;
        tokf[tid] = src[b * S_ + s];
        tokb[tid] = src[b * S_ + (S_ - 1 - s)];
    }
    if (tid < TD_ * B_) {
        int t = tid >> 5, b = tid & 31;
        tokd[tid] = tgt[b * T_ + t];
    }
    if (tid < 2 * 2 * B_ * H_) h_enc[tid] = 0.f;   // [dir][pp][B][H]
    if (tid < 8) bars[tid] = 0u;
}

// ---------------------------------------------------------------------------
// write decoder embeddings into cat[:, 512:768]
// ---------------------------------------------------------------------------
__global__ __launch_bounds__(256)
void emb_cat_kernel(const int* __restrict__ tokd, const float* __restrict__ dec_emb,
                    float* __restrict__ cat)
{
    int row = blockIdx.x;          // row = t*32 + b
    int tid = threadIdx.x;         // 0..255 == E_
    cat[(size_t)row * CATK_ + H_ + tid] = dec_emb[(size_t)tokd[row] * E_ + tid];
}

// ---------------------------------------------------------------------------
// Generic fp32 GEMM (small GEMMs + fallback fc1)
// ---------------------------------------------------------------------------
template<int GATHER, int FC1MAP>
__global__ __launch_bounds__(256)
void gemm128_kernel(const float* __restrict__ A, int lda,
                    const int* __restrict__ tokens, const float* __restrict__ emb,
                    const float* __restrict__ W, int ldw,
                    const float* __restrict__ bias,
                    float* __restrict__ C, int ldc,
                    int M, int N, int K)
{
    __shared__ float As[16][132];
    __shared__ float Ws[16][132];
    (void)N;
    int tid = threadIdx.x;
    int m0 = blockIdx.y * 128, n0 = blockIdx.x * 128;
    int tx = tid & 15, ty = tid >> 4;
    float c[8][8];
#pragma unroll
    for (int i = 0; i < 8; i++)
#pragma unroll
        for (int j = 0; j < 8; j++) c[i][j] = 0.f;

    int arow = tid >> 1;
    int kq = (tid & 1) * 8;

    int am = m0 + arow; if (am >= M) am = M - 1;
    const float* arp;
    if (GATHER) arp = emb + (size_t)tokens[am] * (size_t)K;
    else        arp = A + (size_t)am * (size_t)lda;
    const float* wrp = W + (size_t)(n0 + arow) * (size_t)ldw;

    for (int kb = 0; kb < K; kb += 16) {
        __syncthreads();
        float4 a0 = *(const float4*)(arp + kb + kq);
        float4 a1 = *(const float4*)(arp + kb + kq + 4);
        float4 w0 = *(const float4*)(wrp + kb + kq);
        float4 w1 = *(const float4*)(wrp + kb + kq + 4);
        As[kq + 0][arow] = a0.x; As[kq + 1][arow] = a0.y;
        As[kq + 2][arow] = a0.z; As[kq + 3][arow] = a0.w;
        As[kq + 4][arow] = a1.x; As[kq + 5][arow] = a1.y;
        As[kq + 6][arow] = a1.z; As[kq + 7][arow] = a1.w;
        Ws[kq + 0][arow] = w0.x; Ws[kq + 1][arow] = w0.y;
        Ws[kq + 2][arow] = w0.z; Ws[kq + 3][arow] = w0.w;
        Ws[kq + 4][arow] = w1.x; Ws[kq + 5][arow] = w1.y;
        Ws[kq + 6][arow] = w1.z; Ws[kq + 7][arow] = w1.w;
        __syncthreads();
#pragma unroll
        for (int kk = 0; kk < 16; kk++) {
            float a[8], bb[8];
            *(float4*)&a[0]  = *(const float4*)&As[kk][ty * 8];
            *(float4*)&a[4]  = *(const float4*)&As[kk][ty * 8 + 4];
            *(float4*)&bb[0] = *(const float4*)&Ws[kk][tx * 8];
            *(float4*)&bb[4] = *(const float4*)&Ws[kk][tx * 8 + 4];
#pragma unroll
            for (int i = 0; i < 8; i++)
#pragma unroll
                for (int j = 0; j < 8; j++) c[i][j] += a[i] * bb[j];
        }
    }

#pragma unroll
    for (int i = 0; i < 8; i++) {
        int m = m0 + ty * 8 + i;
        if (m < M) {
            size_t rowoff;
            if (FC1MAP) { int tt = m >> 5, bb2 = m & 31; rowoff = ((size_t)bb2 * T_ + tt) * (size_t)ldc; }
            else        rowoff = (size_t)m * (size_t)ldc;
#pragma unroll
            for (int j = 0; j < 8; j += 4) {
                int n = n0 + tx * 8 + j;
                float4 v;
                v.x = c[i][j + 0] + bias[n + 0];
                v.y = c[i][j + 1] + bias[n + 1];
                v.z = c[i][j + 2] + bias[n + 2];
                v.w = c[i][j + 3] + bias[n + 3];
                *(float4*)(C + rowoff + n) = v;
            }
        }
    }
}

// ---------------------------------------------------------------------------
// PERSISTENT bi-GRU encoder: 128 blocks, grid barrier per step.
// Block = (dir, bh, kc) exactly like the old per-step kernel.
// Tail: enc_fc distributed over all 128 blocks -> hT0 (4-grouped transposed).
// ---------------------------------------------------------------------------
__global__ __launch_bounds__(256)
void enc_coop_kernel(const float* __restrict__ gxf, const float* __restrict__ gxb,
                     const float* __restrict__ Whh_f, const float* __restrict__ bhh_f,
                     const float* __restrict__ Whh_b, const float* __restrict__ bhh_b,
                     float* __restrict__ h_enc, float* __restrict__ enc_bt,
                     const float* __restrict__ fcW, const float* __restrict__ fcb,
                     float* __restrict__ hT0,
                     unsigned* __restrict__ bar_cnt, unsigned* __restrict__ bar_gen)
{
    const int bid = blockIdx.x;
    const int dir = bid >> 6, bh = (bid >> 5) & 1, kc = bid & 31;
    const int tid = threadIdx.x;
    const int bl = tid & 15, kl = tid >> 4;
    const int b = bh * 16 + bl, k = kc * 16 + kl;
    const float* Whh = dir ? Whh_b : Whh_f;
    const float* bhhp = dir ? bhh_b : bhh_f;
    const float* gx  = dir ? gxb : gxf;
    __shared__ float hL[16 * 516];
    const float* wr = Whh + (size_t)k * H_;
    const float* wz = Whh + (size_t)(H_ + k) * H_;
    const float* wn = Whh + (size_t)(2 * H_ + k) * H_;
    const float b_r = bhhp[k], b_z = bhhp[H_ + k], b_n = bhhp[2 * H_ + k];

    for (int t = 0; t < S_; ++t) {
        const int pp = t & 1;
        const float* hin = h_enc + (size_t)(dir * 2 + pp) * B_ * H_;
        float* hout = h_enc + (size_t)(dir * 2 + 1 - pp) * B_ * H_;
        const float* hsrc = hin + (size_t)bh * 16 * H_;
        for (int i = tid * 4; i < 16 * H_; i += 1024) {
            int r = i >> 9, cix = i & (H_ - 1);
            *(float4*)&hL[r * 516 + cix] = *(const float4*)(hsrc + i);
        }
        __syncthreads();
        float ar = 0.f, az = 0.f, an = 0.f;
        const float* hv = &hL[bl * 516];
#pragma unroll 4
        for (int j = 0; j < H_; j += 4) {
            float4 h4 = *(const float4*)(hv + j);
            float4 r4 = *(const float4*)(wr + j);
            float4 z4 = *(const float4*)(wz + j);
            float4 n4 = *(const float4*)(wn + j);
            ar += h4.x * r4.x + h4.y * r4.y + h4.z * r4.z + h4.w * r4.w;
            az += h4.x * z4.x + h4.y * z4.y + h4.z * z4.z + h4.w * z4.w;
            an += h4.x * n4.x + h4.y * n4.y + h4.z * n4.z + h4.w * n4.w;
        }
        const float* gxr = gx + ((size_t)t * B_ + b) * G3_;
        float xr = gxr[k], xz = gxr[H_ + k], xn = gxr[2 * H_ + k];
        float rg = 1.f / (1.f + expf(-(xr + ar + b_r)));
        float zg = 1.f / (1.f + expf(-(xz + az + b_z)));
        float ng = tanhf(xn + rg * (an + b_n));
        float hp = hL[bl * 516 + k];
        float h2 = (1.f - zg) * ng + zg * hp;
        hout[(size_t)b * H_ + k] = h2;
        int s_out = dir ? (S_ - 1 - t) : t;
        enc_bt[((size_t)b * S_ + s_out) * (2 * H_) + dir * H_ + k] = h2;
        grid_bar(bar_cnt, bar_gen, 128);
    }

    // tail: hidden = tanh([hf,hb] @ fcW.T + fcb), 128 blocks x 128 rows
    {
        const int b2 = bid & 31, ih = bid >> 5;   // ih in 0..3
        float* hc = hL;   // reuse (last grid_bar ended with __syncthreads)
        const float* hf  = h_enc + (size_t)b2 * H_;              // dir0 pp0 (final)
        const float* hbk = h_enc + (size_t)(2 * B_ + b2) * H_;   // dir1 pp0 (final)
        for (int i = tid; i < H_; i += 256) { hc[i] = hf[i]; hc[H_ + i] = hbk[i]; }
        __syncthreads();
        if (tid < 128) {
            int i = ih * 128 + tid;
            const float* w = fcW + (size_t)i * (2 * H_);
            float acc = 0.f;
            for (int j = 0; j < 2 * H_; j += 4) {
                float4 a4 = *(const float4*)&hc[j];
                float4 w4 = *(const float4*)(w + j);
                acc += a4.x * w4.x + a4.y * w4.y + a4.z * w4.z + a4.w * w4.w;
            }
            hT0[IDX4(i, b2)] = tanhf(acc + fcb[i]);
        }
    }
}

// ---------------------------------------------------------------------------
// PERSISTENT attention decoder: 128 blocks, 3 phases/step + grid barriers.
// P0: hWh = h @ W_h.T distributed (W_h read once chip-wide)
// P1: per-b attention: scores -> masked softmax -> weighted (blocks 0..31)
// P2: GRU k-sliced (weights read once chip-wide), writes h', cat
// ---------------------------------------------------------------------------
__global__ __launch_bounds__(256)
void dec_coop_kernel(const float* __restrict__ attn_W, const float* __restrict__ attn_v,
                     const float* __restrict__ enc_projB, const float* __restrict__ enc_bt,
                     const int* __restrict__ src,
                     const float* __restrict__ dWhh, const float* __restrict__ dbhh,
                     const float* __restrict__ dWih, const float* __restrict__ gx_emb,
                     float* __restrict__ cat, float* __restrict__ hT,
                     float* __restrict__ hwhT, float* __restrict__ wT,
                     unsigned* __restrict__ bar_cnt, unsigned* __restrict__ bar_gen)
{
    const int bid = blockIdx.x, tid = threadIdx.x;
    __shared__ float sh[1668];         // hwh 512 | vL 512 | aL 128 | ... | red @1664
    __shared__ float part[256][4];
    const int b = tid & 31, kl = tid >> 5;
    const int k4 = kl & 3, half = kl >> 2;
    const int k = bid * 4 + k4;                       // owned output k in [0,512)
    const float* whr = dWhh + (size_t)k * H_;
    const float* whz = dWhh + (size_t)(H_ + k) * H_;
    const float* whn = dWhh + (size_t)(2 * H_ + k) * H_;
    const float* wir = dWih + (size_t)k * DIN_ + E_;
    const float* wiz = dWih + (size_t)(H_ + k) * DIN_ + E_;
    const float* win = dWih + (size_t)(2 * H_ + k) * DIN_ + E_;
    const float* wh_row = attn_W + (size_t)k * G3_;   // W_h row k (cols 0..H)
    const float dbr = dbhh[k], dbz = dbhh[H_ + k], dbn = dbhh[2 * H_ + k];

    for (int t = 0; t < TD_; ++t) {
        const int pp = t & 1;
        const float* hin = hT + (size_t)pp * (H_ * B_);
        float* hnext = hT + (size_t)(1 - pp) * (H_ * B_);
        float* cat_t = cat + (size_t)t * B_ * CATK_;

        // ---- P0: hwhT[k][b] (all blocks; half-split dot + LDS combine) ----
        {
            float acc = 0.f;
            const int j0 = half * 256;
            for (int j = j0; j < j0 + 256; j += 4) {
                float4 h4 = *(const float4*)(hin + IDX4(j, b));
                float4 w4 = *(const float4*)(wh_row + j);
                acc += h4.x * w4.x + h4.y * w4.y + h4.z * w4.z + h4.w * w4.w;
            }
            part[tid][0] = acc;
            __syncthreads();
            if (kl < 4) hwhT[(size_t)bid * 128 + b * 4 + k4] = part[tid][0] + part[tid + 128][0];
        }
        grid_bar(bar_cnt, bar_gen, 128);

        // ---- P1: attention (blocks 0..31, block = batch row) ----
        if (bid < 32) {
            const int ab = bid;
            float* hwh = sh;
            float* vL  = sh + 512;
            float* aL  = sh + 1024;
            float* red = sh + 1664;
            for (int i = tid; i < H_; i += 256) {
                hwh[i] = hwhT[(size_t)(i >> 2) * 128 + ab * 4 + (i & 3)];
                vL[i]  = attn_v[i];
            }
            __syncthreads();
            int wv = tid >> 6, lane = tid & 63;
            for (int so = 0; so < 32; so++) {
                int s = so * 4 + wv;
                const float* pr = enc_projB + ((size_t)ab * S_ + s) * H_;
                float acc = 0.f;
#pragma unroll
                for (int u = 0; u < 8; u++) {
                    int hh = u * 64 + lane;
                    float x = hwh[hh] + pr[hh];
                    float e2 = __expf(2.f * x);
                    acc += vL[hh] * (1.f - 2.f / (e2 + 1.f));
                }
#pragma unroll
                for (int off = 1; off < 64; off <<= 1) acc += __shfl_xor(acc, off);
                if (lane == 0) aL[s] = acc;
            }
            __syncthreads();
            if (tid < S_) aL[tid] = (src[ab * S_ + tid] != 0) ? aL[tid] : -1e10f;
            __syncthreads();
            if (tid < 64) {
                float m = fmaxf(aL[tid], aL[tid + 64]);
#pragma unroll
                for (int off = 1; off < 64; off <<= 1) m = fmaxf(m, __shfl_xor(m, off));
                if (tid == 0) red[0] = m;
            }
            __syncthreads();
            if (tid < S_) aL[tid] = expf(aL[tid] - red[0]);
            __syncthreads();
            if (tid < 64) {
                float sv = aL[tid] + aL[tid + 64];
#pragma unroll
                for (int off = 1; off < 64; off <<= 1) sv += __shfl_xor(sv, off);
                if (tid == 0) red[1] = sv;
            }
            __syncthreads();
            if (tid < S_) aL[tid] = aL[tid] / red[1];
            __syncthreads();
            const float* eb = enc_bt + (size_t)ab * S_ * (2 * H_) + tid * 4;
            float w0 = 0, w1 = 0, w2 = 0, w3 = 0;
            for (int s = 0; s < S_; s++) {
                float a = aL[s];
                float4 v = *(const float4*)(eb + (size_t)s * (2 * H_));
                w0 += a * v.x; w1 += a * v.y; w2 += a * v.z; w3 += a * v.w;
            }
            float4 outv; outv.x = w0; outv.y = w1; outv.z = w2; outv.w = w3;
            *(float4*)(cat_t + (size_t)ab * CATK_ + (H_ + E_) + tid * 4) = outv;
            *(float4*)(wT + (size_t)tid * (B_ * 4) + ab * 4) = outv;   // IDX4(tid*4, ab)
        }
        grid_bar(bar_cnt, bar_gen, 128);

        // ---- P2: GRU (all blocks; k-sliced, half-split + LDS combine) ----
        {
            float p0 = 0.f, p1 = 0.f, p2 = 0.f, p3 = 0.f;
            if (half == 0) {
                // Whh·h (r,z,n) + Wih_n·w cols 0..512
                for (int j = 0; j < H_; j += 4) {
                    float4 h4 = *(const float4*)(hin + IDX4(j, b));
                    float4 r4 = *(const float4*)(whr + j);
                    float4 z4 = *(const float4*)(whz + j);
                    float4 n4 = *(const float4*)(whn + j);
                    p0 += h4.x * r4.x + h4.y * r4.y + h4.z * r4.z + h4.w * r4.w;
                    p1 += h4.x * z4.x + h4.y * z4.y + h4.z * z4.z + h4.w * z4.w;
                    p2 += h4.x * n4.x + h4.y * n4.y + h4.z * n4.z + h4.w * n4.w;
                }
                for (int c = 0; c < 512; c += 4) {
                    float4 w4 = *(const float4*)(wT + IDX4(c, b));
                    float4 n4 = *(const float4*)(win + c);
                    p3 += w4.x * n4.x + w4.y * n4.y + w4.z * n4.z + w4.w * n4.w;
                }
                // p0=hr p1=hz p2=hn p3=xn_lo
            } else {
                // Wih_r, Wih_z full; Wih_n cols 512..1024
                for (int c = 0; c < 512; c += 4) {
                    float4 w4 = *(const float4*)(wT + IDX4(c, b));
                    float4 r4 = *(const float4*)(wir + c);
                    float4 z4 = *(const float4*)(wiz + c);
                    p0 += w4.x * r4.x + w4.y * r4.y + w4.z * r4.z + w4.w * r4.w;
                    p1 += w4.x * z4.x + w4.y * z4.y + w4.z * z4.z + w4.w * z4.w;
                }
                for (int c = 512; c < 1024; c += 4) {
                    float4 w4 = *(const float4*)(wT + IDX4(c, b));
                    float4 r4 = *(const float4*)(wir + c);
                    float4 z4 = *(const float4*)(wiz + c);
                    float4 n4 = *(const float4*)(win + c);
                    p0 += w4.x * r4.x + w4.y * r4.y + w4.z * r4.z + w4.w * r4.w;
                    p1 += w4.x * z4.x + w4.y * z4.y + w4.z * z4.z + w4.w * z4.w;
                    p2 += w4.x * n4.x + w4.y * n4.y + w4.z * n4.z + w4.w * n4.w;
                }
                // p0=xr p1=xz p2=xn_hi
            }
            part[tid][0] = p0; part[tid][1] = p1; part[tid][2] = p2; part[tid][3] = p3;
            __syncthreads();
            if (kl < 4) {
                float hr  = part[tid][0], hz = part[tid][1], hn = part[tid][2], xn0 = part[tid][3];
                float xr  = part[tid + 128][0], xz = part[tid + 128][1], xn1 = part[tid + 128][2];
                const float* gxe = gx_emb + ((size_t)t * B_ + b) * G3_;
                float gr = gxe[k], gz = gxe[H_ + k], gn = gxe[2 * H_ + k];
                float rg = 1.f / (1.f + expf(-(gr + xr + hr + dbr)));
                float zg = 1.f / (1.f + expf(-(gz + xz + hz + dbz)));
                float ng = tanhf(gn + xn0 + xn1 + rg * (hn + dbn));
                float hp = hin[IDX4(k, b)];
                float h2 = (1.f - zg) * ng + zg * hp;
                hnext[IDX4(k, b)] = h2;
                cat_t[(size_t)b * CATK_ + k] = h2;
            }
        }
        grid_bar(bar_cnt, bar_gen, 128);
    }
}

// ---------------------------------------------------------------------------
// split cat (fp32 [2016][1792]) into bf16 hi/lo, padded to 2048 rows (zeros)
// ---------------------------------------------------------------------------
__global__ __launch_bounds__(256)
void splitA_kernel(const float* __restrict__ cat,
                   unsigned short* __restrict__ Ahi, unsigned short* __restrict__ Alo)
{
    size_t i4 = ((size_t)blockIdx.x * 256 + threadIdx.x) * 4;
    if (i4 >= (size_t)MPAD_ * CATK_) return;
    size_t row = i4 / CATK_;
    float4 v;
    if (row < (size_t)TD_ * B_) v = *(const float4*)(cat + i4);
    else { v.x = v.y = v.z = v.w = 0.f; }
    float f[4] = {v.x, v.y, v.z, v.w};
    unsigned short h[4], l[4];
#pragma unroll
    for (int j = 0; j < 4; j++) {
        h[j] = bf16_rne(f[j]);
        float hf = __uint_as_float((unsigned)h[j] << 16);
        l[j] = bf16_rne(f[j] - hf);
    }
    *(ushort4*)(Ahi + i4) = make_ushort4(h[0], h[1], h[2], h[3]);
    *(ushort4*)(Alo + i4) = make_ushort4(l[0], l[1], l[2], l[3]);
}

// ---------------------------------------------------------------------------
// fc1 via split-bf16 MFMA (hh + hl + lh): fp32-accurate logits.
// ---------------------------------------------------------------------------
__global__ __launch_bounds__(256)
void fc1_mfma_kernel(const unsigned short* __restrict__ Ahi,
                     const unsigned short* __restrict__ Alo,
                     const float* __restrict__ W,
                     const float* __restrict__ bias,
                     float* __restrict__ C)
{
    __shared__ unsigned short lA[2][128][40];
    __shared__ unsigned short lW[2][128][40];
    const int tid = threadIdx.x;
    const int m0 = blockIdx.x * 128, n0 = blockIdx.y * 128;
    const int w = tid >> 6, lane = tid & 63;
    const int wm = w >> 1, wn = w & 1;
    const int frow = lane & 15, fk = (lane >> 4) * 8;

    f32x4 acc[4][4];
#pragma unroll
    for (int mi = 0; mi < 4; mi++)
#pragma unroll
        for (int ni = 0; ni < 4; ni++) acc[mi][ni] = (f32x4){0.f, 0.f, 0.f, 0.f};

    const int srow = tid >> 1;
    const int skq = (tid & 1) * 16;

    const unsigned short* gAhi = Ahi + (size_t)(m0 + srow) * CATK_ + skq;
    const unsigned short* gAlo = Alo + (size_t)(m0 + srow) * CATK_ + skq;
    const float*          gW   = W   + (size_t)(n0 + srow) * CATK_ + skq;

    int4 rAh0, rAh1, rAl0, rAl1;
    float4 rW0, rW1, rW2, rW3;

#define FC1_LOAD(kb)                                        \
    do {                                                    \
        rAh0 = *(const int4*)(gAhi + (kb));                 \
        rAh1 = *(const int4*)(gAhi + (kb) + 8);             \
        rAl0 = *(const int4*)(gAlo + (kb));                 \
        rAl1 = *(const int4*)(gAlo + (kb) + 8);             \
        rW0  = *(const float4*)(gW + (kb));                 \
        rW1  = *(const float4*)(gW + (kb) + 4);             \
        rW2  = *(const float4*)(gW + (kb) + 8);             \
        rW3  = *(const float4*)(gW + (kb) + 12);            \
    } while (0)

    FC1_LOAD(0);

    for (int kb = 0; kb < CATK_; kb += 32) {
        __syncthreads();
        *(int4*)&lA[0][srow][skq]     = rAh0;
        *(int4*)&lA[0][srow][skq + 8] = rAh1;
        *(int4*)&lA[1][srow][skq]     = rAl0;
        *(int4*)&lA[1][srow][skq + 8] = rAl1;
        {
            float f[16] = {rW0.x, rW0.y, rW0.z, rW0.w, rW1.x, rW1.y, rW1.z, rW1.w,
                           rW2.x, rW2.y, rW2.z, rW2.w, rW3.x, rW3.y, rW3.z, rW3.w};
            unsigned hp[8], lp[8];
#pragma unroll
            for (int j = 0; j < 8; j++) {
                float x0 = f[2 * j], x1 = f[2 * j + 1];
                unsigned short h0 = bf16_rne(x0), h1 = bf16_rne(x1);
                float r0 = x0 - __uint_as_float((unsigned)h0 << 16);
                float r1 = x1 - __uint_as_float((unsigned)h1 << 16);
                hp[j] = (unsigned)h0 | ((unsigned)h1 << 16);
                lp[j] = (unsigned)bf16_rne(r0) | ((unsigned)bf16_rne(r1) << 16);
            }
            *(int4*)&lW[0][srow][skq]     = make_int4(hp[0], hp[1], hp[2], hp[3]);
            *(int4*)&lW[0][srow][skq + 8] = make_int4(hp[4], hp[5], hp[6], hp[7]);
            *(int4*)&lW[1][srow][skq]     = make_int4(lp[0], lp[1], lp[2], lp[3]);
            *(int4*)&lW[1][srow][skq + 8] = make_int4(lp[4], lp[5], lp[6], lp[7]);
        }
        __syncthreads();
        if (kb + 32 < CATK_) FC1_LOAD(kb + 32);

        bf16x8 a[2][4];
#pragma unroll
        for (int mi = 0; mi < 4; mi++) {
            int r = wm * 64 + mi * 16 + frow;
            a[0][mi] = *(const bf16x8*)&lA[0][r][fk];
            a[1][mi] = *(const bf16x8*)&lA[1][r][fk];
        }
#pragma unroll
        for (int ni = 0; ni < 4; ni++) {
            int r = wn * 64 + ni * 16 + frow;
            bf16x8 bh = *(const bf16x8*)&lW[0][r][fk];
            bf16x8 bl = *(const bf16x8*)&lW[1][r][fk];
#pragma unroll
            for (int mi = 0; mi < 4; mi++) {
                acc[mi][ni] = __builtin_amdgcn_mfma_f32_16x16x32_bf16(a[0][mi], bh, acc[mi][ni], 0, 0, 0);
                acc[mi][ni] = __builtin_amdgcn_mfma_f32_16x16x32_bf16(a[1][mi], bh, acc[mi][ni], 0, 0, 0);
                acc[mi][ni] = __builtin_amdgcn_mfma_f32_16x16x32_bf16(a[0][mi], bl, acc[mi][ni], 0, 0, 0);
            }
        }
    }
#undef FC1_LOAD

#pragma unroll
    for (int ni = 0; ni < 4; ni++) {
        int col = n0 + wn * 64 + ni * 16 + frow;
        float bc = bias[col];
#pragma unroll
        for (int mi = 0; mi < 4; mi++) {
            int mbase = m0 + wm * 64 + mi * 16 + (lane >> 4) * 4;
            f32x4 v = acc[mi][ni];
#pragma unroll
            for (int r = 0; r < 4; r++) {
                int m = mbase + r;
                if (m < TD_ * B_) {
                    int tt = m >> 5, bb2 = m & 31;
                    C[((size_t)bb2 * T_ + tt) * V_ + col] = v[r] + bc;
                }
            }
        }
    }
}

// ---------------------------------------------------------------------------
__global__ __launch_bounds__(256)
void argmax_kernel(const float* __restrict__ outp, float* __restrict__ preds)
{
    int row = blockIdx.x;
    int t = row >> 5, b = row & 31;
    const float* p = outp + ((size_t)b * T_ + t) * V_;
    int tid = threadIdx.x;
    float best = -3.4e38f; int bi = V_;
    for (int i = tid; i < V_; i += 256) {
        float v = p[i];
        if (v > best) { best = v; bi = i; }
    }
    __shared__ float bv[256];
    __shared__ int bidx[256];
    bv[tid] = best; bidx[tid] = bi;
    __syncthreads();
    for (int off = 128; off > 0; off >>= 1) {
        if (tid < off) {
            float v2 = bv[tid + off]; int i2 = bidx[tid + off];
            if (v2 > bv[tid] || (v2 == bv[tid] && i2 < bidx[tid])) { bv[tid] = v2; bidx[tid] = i2; }
        }
        __syncthreads();
    }
    if (tid == 0) preds[(size_t)b * T_ + t] = (float)bidx[0];
}

// ---------------------------------------------------------------------------
__global__ __launch_bounds__(256)
void zero_tail_kernel(float* __restrict__ outp, float* __restrict__ preds)
{
    int tid = blockIdx.x * 256 + threadIdx.x;
    if (tid < B_ * V_) {
        int b = tid / V_;
        int c = tid % V_;
        outp[((size_t)b * T_ + (T_ - 1)) * V_ + c] = 0.f;
    }
    if (tid < B_) preds[(size_t)tid * T_ + (T_ - 1)] = 0.f;
}

// ---------------------------------------------------------------------------
extern "C" void kernel_launch(void* const* d_in, const int* in_sizes, int n_in,
                              void* d_out, int out_size, void* d_ws, size_t ws_size,
                              hipStream_t stream)
{
    (void)in_sizes; (void)n_in; (void)out_size;
    const int*   src     = (const int*)d_in[0];
    const int*   tgt     = (const int*)d_in[1];
    const float* enc_emb = (const float*)d_in[2];
    const float* Wih_f   = (const float*)d_in[3];
    const float* Whh_f   = (const float*)d_in[4];
    const float* bih_f   = (const float*)d_in[5];
    const float* bhh_f   = (const float*)d_in[6];
    const float* Wih_b   = (const float*)d_in[7];
    const float* Whh_b   = (const float*)d_in[8];
    const float* bih_b   = (const float*)d_in[9];
    const float* bhh_b   = (const float*)d_in[10];
    const float* fcW     = (const float*)d_in[11];
    const float* fcb     = (const float*)d_in[12];
    const float* dec_emb = (const float*)d_in[13];
    const float* attn_W  = (const float*)d_in[14];
    const float* attn_b  = (const float*)d_in[15];
    const float* attn_v  = (const float*)d_in[16];
    const float* dWih    = (const float*)d_in[17];
    const float* dWhh    = (const float*)d_in[18];
    const float* dbih    = (const float*)d_in[19];
    const float* dbhh    = (const float*)d_in[20];
    const float* fc1W    = (const float*)d_in[21];
    const float* fc1b    = (const float*)d_in[22];
    (void)dbih;

    // workspace layout
    float* ws     = (float*)d_ws;
    float* cat    = ws;                                  // 3,612,672 f
    float* gx_emb = cat + (size_t)TD_ * B_ * CATK_;      // 3,096,576 f
    float* h_enc  = gx_emb + (size_t)TD_ * B_ * G3_;     // 65,536 f
    float* hT     = h_enc + 2 * 2 * B_ * H_;             // 2*16384 f (4-grouped transposed h)
    float* hwhT   = hT + 2 * H_ * B_;                    // 16,384 f
    float* wT     = hwhT + H_ * B_;                      // 32,768 f
    int*   tokf   = (int*)(wT + 2 * H_ * B_);            // 4096 i
    int*   tokb   = tokf + S_ * B_;                      // 4096 i
    int*   tokd   = tokb + S_ * B_;                      // 2016 -> pad 4096
    unsigned* bars = (unsigned*)(tokd + 4096);           // 16 u (enc: 0,1; dec: 2,3)
    unsigned short* Ahi = (unsigned short*)(bars + 16);
    unsigned short* Alo = Ahi + (size_t)MPAD_ * CATK_;
    size_t ws_req = (size_t)((char*)(Alo + (size_t)MPAD_ * CATK_) - (char*)d_ws);
    const bool use_mfma = (ws_size >= ws_req);

    // d_out doubles as phase-local scratch (fully overwritten by fc1 + zero_tail)
    float* dout      = (float*)d_out;
    float* gxf       = dout;
    float* gxb       = dout + (size_t)S_ * B_ * G3_;
    float* enc_bt    = dout + (size_t)2 * S_ * B_ * G3_;
    float* enc_projB = enc_bt + (size_t)B_ * S_ * 2 * H_;
    float* preds     = dout + (size_t)B_ * T_ * V_;

    dim3 thr(256);

    hipLaunchKernelGGL(prep_kernel, dim3(256), thr, 0, stream, src, tgt, tokf, tokb, tokd, h_enc, bars);
    hipLaunchKernelGGL(emb_cat_kernel, dim3(TD_ * B_), thr, 0, stream, tokd, dec_emb, cat);

    hipLaunchKernelGGL((gemm128_kernel<1, 0>), dim3(G3_ / 128, (S_ * B_) / 128), thr, 0, stream,
                       (const float*)nullptr, 0, tokf, enc_emb, Wih_f, E_, bih_f,
                       gxf, G3_, S_ * B_, G3_, E_);
    hipLaunchKernelGGL((gemm128_kernel<1, 0>), dim3(G3_ / 128, (S_ * B_) / 128), thr, 0, stream,
                       (const float*)nullptr, 0, tokb, enc_emb, Wih_b, E_, bih_b,
                       gxb, G3_, S_ * B_, G3_, E_);

    // whole encoder recurrence + enc_fc in ONE launch
    hipLaunchKernelGGL(enc_coop_kernel, dim3(128), thr, 0, stream,
                       gxf, gxb, Whh_f, bhh_f, Whh_b, bhh_b, h_enc, enc_bt,
                       fcW, fcb, hT, bars + 0, bars + 1);

    hipLaunchKernelGGL((gemm128_kernel<0, 0>), dim3(H_ / 128, (B_ * S_) / 128), thr, 0, stream,
                       enc_bt, 2 * H_, (const int*)nullptr, (const float*)nullptr,
                       attn_W + H_, G3_, attn_b, enc_projB, H_, B_ * S_, H_, 2 * H_);

    hipLaunchKernelGGL((gemm128_kernel<1, 0>), dim3(G3_ / 128, (TD_ * B_ + 127) / 128), thr, 0, stream,
                       (const float*)nullptr, 0, tokd, dec_emb, dWih, DIN_, dbih,
                       gx_emb, G3_, TD_ * B_, G3_, E_);

    // whole decoder recurrence in ONE launch
    hipLaunchKernelGGL(dec_coop_kernel, dim3(128), thr, 0, stream,
                       attn_W, attn_v, enc_projB, enc_bt, src,
                       dWhh, dbhh, dWih, gx_emb, cat, hT, hwhT, wT,
                       bars + 2, bars + 3);

    if (use_mfma) {
        hipLaunchKernelGGL(splitA_kernel, dim3((MPAD_ * CATK_ / 4 + 255) / 256), thr, 0, stream,
                           cat, Ahi, Alo);
        hipLaunchKernelGGL(fc1_mfma_kernel, dim3(MPAD_ / 128, V_ / 128), thr, 0, stream,
                           Ahi, Alo, fc1W, fc1b, dout);
    } else {
        hipLaunchKernelGGL((gemm128_kernel<0, 1>), dim3(V_ / 128, (TD_ * B_ + 127) / 128), thr, 0, stream,
                           cat, CATK_, (const int*)nullptr, (const float*)nullptr,
                           fc1W, CATK_, fc1b, dout, V_, TD_ * B_, V_, CATK_);
    }

    hipLaunchKernelGGL(argmax_kernel, dim3(TD_ * B_), thr, 0, stream, dout, preds);
    hipLaunchKernelGGL(zero_tail_kernel, dim3((B_ * V_ + 255) / 256), thr, 0, stream, dout, preds);
}

// Round 4
// 13357.387 us; speedup vs baseline: 1.4326x; 1.1976x over previous
//
#include <hip/hip_runtime.h>

#define V_ 32000
#define E_ 256
#define H_ 512
#define B_ 32
#define S_ 128
#define T_ 64
#define TD_ 63        // decoder steps (T-1)
#define G3_ 1536      // 3*H
#define CATK_ 1792    // H + E + 2H
#define DIN_ 1280     // E + 2H
#define MPAD_ 2048    // padded M for fc1 MFMA

typedef __attribute__((ext_vector_type(8))) short bf16x8;
typedef __attribute__((ext_vector_type(4))) float f32x4;

__device__ inline unsigned short bf16_rne(float x) {
    unsigned u = __float_as_uint(x);
    unsigned r = u + 0x7FFFu + ((u >> 16) & 1u);
    return (unsigned short)(r >> 16);
}

// 4-grouped transposed index for h/weighted vectors: element j of batch b
#define IDX4(j, b) (((size_t)((j) >> 2) * (B_ * 4)) + (b) * 4 + ((j) & 3))

// ---------------------------------------------------------------------------
// FAST hierarchical grid barrier for 128 blocks: 8 groups x 16.
// Layout (uints): group g: cnt @ g*64, gen @ g*64+32 ; top: cnt @ 512, gen @ 544.
// Relaxed polls (no per-poll cache maintenance!), acq_rel arrivals,
// single agent-acquire fence at exit.
// ---------------------------------------------------------------------------
__device__ __forceinline__ void fast_bar128(unsigned* bars)
{
    __syncthreads();
    if (threadIdx.x == 0) {
        const int g = (int)(blockIdx.x >> 4);
        unsigned* gcnt = bars + g * 64;
        unsigned* ggen = gcnt + 32;
        unsigned* tcnt = bars + 512;
        unsigned* tgen = bars + 544;
        unsigned g0 = __hip_atomic_load(ggen, __ATOMIC_RELAXED, __HIP_MEMORY_SCOPE_AGENT);
        unsigned a  = __hip_atomic_fetch_add(gcnt, 1u, __ATOMIC_ACQ_REL, __HIP_MEMORY_SCOPE_AGENT);
        if (a == 15u) {            // last of group -> group leader this round
            unsigned t0 = __hip_atomic_load(tgen, __ATOMIC_RELAXED, __HIP_MEMORY_SCOPE_AGENT);
            unsigned ta = __hip_atomic_fetch_add(tcnt, 1u, __ATOMIC_ACQ_REL, __HIP_MEMORY_SCOPE_AGENT);
            if (ta == 7u) {        // last group overall
                __hip_atomic_store(tcnt, 0u, __ATOMIC_RELAXED, __HIP_MEMORY_SCOPE_AGENT);
                __hip_atomic_store(tgen, t0 + 1u, __ATOMIC_RELEASE, __HIP_MEMORY_SCOPE_AGENT);
            } else {
                while (__hip_atomic_load(tgen, __ATOMIC_RELAXED, __HIP_MEMORY_SCOPE_AGENT) == t0)
                    __builtin_amdgcn_s_sleep(1);
            }
            __hip_atomic_store(gcnt, 0u, __ATOMIC_RELAXED, __HIP_MEMORY_SCOPE_AGENT);
            __hip_atomic_store(ggen, g0 + 1u, __ATOMIC_RELEASE, __HIP_MEMORY_SCOPE_AGENT);
        } else {
            while (__hip_atomic_load(ggen, __ATOMIC_RELAXED, __HIP_MEMORY_SCOPE_AGENT) == g0)
                __builtin_amdgcn_s_sleep(2);
        }
        __builtin_amdgcn_fence(__ATOMIC_ACQUIRE, "agent");   // one inv per barrier
    }
    __syncthreads();
}

// ---------------------------------------------------------------------------
// prep: token permutations + zero encoder hidden state + zero barrier region
// ---------------------------------------------------------------------------
__global__ __launch_bounds__(256)
void prep_kernel(const int* __restrict__ src, const int* __restrict__ tgt,
                 int* __restrict__ tokf, int* __restrict__ tokb, int* __restrict__ tokd,
                 float* __restrict__ h_enc, unsigned* __restrict__ bars)
{
    int tid = blockIdx.x * 256 + threadIdx.x;
    if (tid < S_ * B_) {
        int s = tid >> 5, b = tid & 31;
        tokf[tid] = src[b * S_ + s];
        tokb[tid] = src[b * S_ + (S_ - 1 - s)];
    }
    if (tid < TD_ * B_) {
        int t = tid >> 5, b = tid & 31;
        tokd[tid] = tgt[b * T_ + t];
    }
    if (tid < 2 * 2 * B_ * H_) h_enc[tid] = 0.f;   // [dir][pp][B][H]
    if (tid < 4096) bars[tid] = 0u;
}

// ---------------------------------------------------------------------------
// write decoder embeddings into cat[:, 512:768]
// ---------------------------------------------------------------------------
__global__ __launch_bounds__(256)
void emb_cat_kernel(const int* __restrict__ tokd, const float* __restrict__ dec_emb,
                    float* __restrict__ cat)
{
    int row = blockIdx.x;          // row = t*32 + b
    int tid = threadIdx.x;         // 0..255 == E_
    cat[(size_t)row * CATK_ + H_ + tid] = dec_emb[(size_t)tokd[row] * E_ + tid];
}

// ---------------------------------------------------------------------------
// Generic fp32 GEMM (small GEMMs + fallback fc1)
// ---------------------------------------------------------------------------
template<int GATHER, int FC1MAP>
__global__ __launch_bounds__(256)
void gemm128_kernel(const float* __restrict__ A, int lda,
                    const int* __restrict__ tokens, const float* __restrict__ emb,
                    const float* __restrict__ W, int ldw,
                    const float* __restrict__ bias,
                    float* __restrict__ C, int ldc,
                    int M, int N, int K)
{
    __shared__ float As[16][132];
    __shared__ float Ws[16][132];
    (void)N;
    int tid = threadIdx.x;
    int m0 = blockIdx.y * 128, n0 = blockIdx.x * 128;
    int tx = tid & 15, ty = tid >> 4;
    float c[8][8];
#pragma unroll
    for (int i = 0; i < 8; i++)
#pragma unroll
        for (int j = 0; j < 8; j++) c[i][j] = 0.f;

    int arow = tid >> 1;
    int kq = (tid & 1) * 8;

    int am = m0 + arow; if (am >= M) am = M - 1;
    const float* arp;
    if (GATHER) arp = emb + (size_t)tokens[am] * (size_t)K;
    else        arp = A + (size_t)am * (size_t)lda;
    const float* wrp = W + (size_t)(n0 + arow) * (size_t)ldw;

    for (int kb = 0; kb < K; kb += 16) {
        __syncthreads();
        float4 a0 = *(const float4*)(arp + kb + kq);
        float4 a1 = *(const float4*)(arp + kb + kq + 4);
        float4 w0 = *(const float4*)(wrp + kb + kq);
        float4 w1 = *(const float4*)(wrp + kb + kq + 4);
        As[kq + 0][arow] = a0.x; As[kq + 1][arow] = a0.y;
        As[kq + 2][arow] = a0.z; As[kq + 3][arow] = a0.w;
        As[kq + 4][arow] = a1.x; As[kq + 5][arow] = a1.y;
        As[kq + 6][arow] = a1.z; As[kq + 7][arow] = a1.w;
        Ws[kq + 0][arow] = w0.x; Ws[kq + 1][arow] = w0.y;
        Ws[kq + 2][arow] = w0.z; Ws[kq + 3][arow] = w0.w;
        Ws[kq + 4][arow] = w1.x; Ws[kq + 5][arow] = w1.y;
        Ws[kq + 6][arow] = w1.z; Ws[kq + 7][arow] = w1.w;
        __syncthreads();
#pragma unroll
        for (int kk = 0; kk < 16; kk++) {
            float a[8], bb[8];
            *(float4*)&a[0]  = *(const float4*)&As[kk][ty * 8];
            *(float4*)&a[4]  = *(const float4*)&As[kk][ty * 8 + 4];
            *(float4*)&bb[0] = *(const float4*)&Ws[kk][tx * 8];
            *(float4*)&bb[4] = *(const float4*)&Ws[kk][tx * 8 + 4];
#pragma unroll
            for (int i = 0; i < 8; i++)
#pragma unroll
                for (int j = 0; j < 8; j++) c[i][j] += a[i] * bb[j];
        }
    }

#pragma unroll
    for (int i = 0; i < 8; i++) {
        int m = m0 + ty * 8 + i;
        if (m < M) {
            size_t rowoff;
            if (FC1MAP) { int tt = m >> 5, bb2 = m & 31; rowoff = ((size_t)bb2 * T_ + tt) * (size_t)ldc; }
            else        rowoff = (size_t)m * (size_t)ldc;
#pragma unroll
            for (int j = 0; j < 8; j += 4) {
                int n = n0 + tx * 8 + j;
                float4 v;
                v.x = c[i][j + 0] + bias[n + 0];
                v.y = c[i][j + 1] + bias[n + 1];
                v.z = c[i][j + 2] + bias[n + 2];
                v.w = c[i][j + 3] + bias[n + 3];
                *(float4*)(C + rowoff + n) = v;
            }
        }
    }
}

// ---------------------------------------------------------------------------
// PERSISTENT bi-GRU encoder: 128 blocks, fast grid barrier per step.
// Tail: enc_fc distributed over all 128 blocks -> hT0 (4-grouped transposed).
// ---------------------------------------------------------------------------
__global__ __launch_bounds__(256)
void enc_coop_kernel(const float* __restrict__ gxf, const float* __restrict__ gxb,
                     const float* __restrict__ Whh_f, const float* __restrict__ bhh_f,
                     const float* __restrict__ Whh_b, const float* __restrict__ bhh_b,
                     float* __restrict__ h_enc, float* __restrict__ enc_bt,
                     const float* __restrict__ fcW, const float* __restrict__ fcb,
                     float* __restrict__ hT0, unsigned* __restrict__ bars)
{
    const int bid = blockIdx.x;
    const int dir = bid >> 6, bh = (bid >> 5) & 1, kc = bid & 31;
    const int tid = threadIdx.x;
    const int bl = tid & 15, kl = tid >> 4;
    const int b = bh * 16 + bl, k = kc * 16 + kl;
    const float* Whh = dir ? Whh_b : Whh_f;
    const float* bhhp = dir ? bhh_b : bhh_f;
    const float* gx  = dir ? gxb : gxf;
    __shared__ float hL[16 * 516];
    const float* wr = Whh + (size_t)k * H_;
    const float* wz = Whh + (size_t)(H_ + k) * H_;
    const float* wn = Whh + (size_t)(2 * H_ + k) * H_;
    const float b_r = bhhp[k], b_z = bhhp[H_ + k], b_n = bhhp[2 * H_ + k];

    for (int t = 0; t < S_; ++t) {
        const int pp = t & 1;
        const float* hin = h_enc + (size_t)(dir * 2 + pp) * B_ * H_;
        float* hout = h_enc + (size_t)(dir * 2 + 1 - pp) * B_ * H_;
        const float* hsrc = hin + (size_t)bh * 16 * H_;
        for (int i = tid * 4; i < 16 * H_; i += 1024) {
            int r = i >> 9, cix = i & (H_ - 1);
            *(float4*)&hL[r * 516 + cix] = *(const float4*)(hsrc + i);
        }
        __syncthreads();
        float ar = 0.f, az = 0.f, an = 0.f;
        const float* hv = &hL[bl * 516];
#pragma unroll 4
        for (int j = 0; j < H_; j += 4) {
            float4 h4 = *(const float4*)(hv + j);
            float4 r4 = *(const float4*)(wr + j);
            float4 z4 = *(const float4*)(wz + j);
            float4 n4 = *(const float4*)(wn + j);
            ar += h4.x * r4.x + h4.y * r4.y + h4.z * r4.z + h4.w * r4.w;
            az += h4.x * z4.x + h4.y * z4.y + h4.z * z4.z + h4.w * z4.w;
            an += h4.x * n4.x + h4.y * n4.y + h4.z * n4.z + h4.w * n4.w;
        }
        const float* gxr = gx + ((size_t)t * B_ + b) * G3_;
        float xr = gxr[k], xz = gxr[H_ + k], xn = gxr[2 * H_ + k];
        float rg = 1.f / (1.f + expf(-(xr + ar + b_r)));
        float zg = 1.f / (1.f + expf(-(xz + az + b_z)));
        float ng = tanhf(xn + rg * (an + b_n));
        float hp = hL[bl * 516 + k];
        float h2 = (1.f - zg) * ng + zg * hp;
        hout[(size_t)b * H_ + k] = h2;
        int s_out = dir ? (S_ - 1 - t) : t;
        enc_bt[((size_t)b * S_ + s_out) * (2 * H_) + dir * H_ + k] = h2;
        fast_bar128(bars);
    }

    // tail: hidden = tanh([hf,hb] @ fcW.T + fcb), 128 blocks x 128 rows
    {
        const int b2 = bid & 31, ih = bid >> 5;   // ih in 0..3
        float* hc = hL;   // reuse (last fast_bar ended with __syncthreads)
        const float* hf  = h_enc + (size_t)b2 * H_;              // dir0 pp0 (final)
        const float* hbk = h_enc + (size_t)(2 * B_ + b2) * H_;   // dir1 pp0 (final)
        for (int i = tid; i < H_; i += 256) { hc[i] = hf[i]; hc[H_ + i] = hbk[i]; }
        __syncthreads();
        if (tid < 128) {
            int i = ih * 128 + tid;
            const float* w = fcW + (size_t)i * (2 * H_);
            float acc = 0.f;
            for (int j = 0; j < 2 * H_; j += 4) {
                float4 a4 = *(const float4*)&hc[j];
                float4 w4 = *(const float4*)(w + j);
                acc += a4.x * w4.x + a4.y * w4.y + a4.z * w4.z + a4.w * w4.w;
            }
            hT0[IDX4(i, b2)] = tanhf(acc + fcb[i]);
        }
    }
}

// ---------------------------------------------------------------------------
// PERSISTENT attention decoder: 128 blocks, 3 phases/step + fast barriers.
// P0: hwhT = W_h·h distributed over 128 blocks (4 k's each)
// P1: blocks 0..31: per-b attention -> weighted;  blocks 32..127: ghh = Whh·h+bhh
// P2: all blocks: Wih·w (k-sliced) + combine -> h', cat
// ---------------------------------------------------------------------------
__global__ __launch_bounds__(256)
void dec_coop_kernel(const float* __restrict__ attn_W, const float* __restrict__ attn_v,
                     const float* __restrict__ enc_projB, const float* __restrict__ enc_bt,
                     const int* __restrict__ src,
                     const float* __restrict__ dWhh, const float* __restrict__ dbhh,
                     const float* __restrict__ dWih, const float* __restrict__ gx_emb,
                     float* __restrict__ cat, float* __restrict__ hT,
                     float* __restrict__ hwhT, float* __restrict__ wT,
                     float* __restrict__ ghh, unsigned* __restrict__ bars)
{
    const int bid = blockIdx.x, tid = threadIdx.x;
    __shared__ float sh[1668];         // hwh 512 | vL 512 | aL 128 | ... | red @1664
    __shared__ float part[256][4];
    const int b = tid & 31, kl = tid >> 5;
    const int k4 = kl & 3, half = kl >> 2;
    const int k = bid * 4 + k4;                       // owned output k in [0,512)
    const float* wir = dWih + (size_t)k * DIN_ + E_;
    const float* wiz = dWih + (size_t)(H_ + k) * DIN_ + E_;
    const float* win = dWih + (size_t)(2 * H_ + k) * DIN_ + E_;
    const float* wh_row = attn_W + (size_t)k * G3_;   // W_h row k (cols 0..H)

    for (int t = 0; t < TD_; ++t) {
        const int pp = t & 1;
        const float* hin = hT + (size_t)pp * (H_ * B_);
        float* hnext = hT + (size_t)(1 - pp) * (H_ * B_);
        float* cat_t = cat + (size_t)t * B_ * CATK_;

        // ---- P0: hwhT[k][b] (all blocks; half-split dot + LDS combine) ----
        {
            float acc = 0.f;
            const int j0 = half * 256;
            for (int j = j0; j < j0 + 256; j += 4) {
                float4 h4 = *(const float4*)(hin + IDX4(j, b));
                float4 w4 = *(const float4*)(wh_row + j);
                acc += h4.x * w4.x + h4.y * w4.y + h4.z * w4.z + h4.w * w4.w;
            }
            part[tid][0] = acc;
            __syncthreads();
            if (kl < 4) hwhT[(size_t)bid * 128 + b * 4 + k4] = part[tid][0] + part[tid + 128][0];
        }
        fast_bar128(bars);

        // ---- P1: attention (blocks 0..31) | ghh = Whh·h + bhh (blocks 32..127) ----
        if (bid < 32) {
            const int ab = bid;
            float* hwh = sh;
            float* vL  = sh + 512;
            float* aL  = sh + 1024;
            float* red = sh + 1664;
            for (int i = tid; i < H_; i += 256) {
                hwh[i] = hwhT[(size_t)(i >> 2) * 128 + ab * 4 + (i & 3)];
                vL[i]  = attn_v[i];
            }
            __syncthreads();
            int wv = tid >> 6, lane = tid & 63;
            for (int so = 0; so < 32; so++) {
                int s = so * 4 + wv;
                const float* pr = enc_projB + ((size_t)ab * S_ + s) * H_;
                float acc = 0.f;
#pragma unroll
                for (int u = 0; u < 8; u++) {
                    int hh = u * 64 + lane;
                    float x = hwh[hh] + pr[hh];
                    float e2 = __expf(2.f * x);
                    acc += vL[hh] * (1.f - 2.f / (e2 + 1.f));
                }
#pragma unroll
                for (int off = 1; off < 64; off <<= 1) acc += __shfl_xor(acc, off);
                if (lane == 0) aL[s] = acc;
            }
            __syncthreads();
            if (tid < S_) aL[tid] = (src[ab * S_ + tid] != 0) ? aL[tid] : -1e10f;
            __syncthreads();
            if (tid < 64) {
                float m = fmaxf(aL[tid], aL[tid + 64]);
#pragma unroll
                for (int off = 1; off < 64; off <<= 1) m = fmaxf(m, __shfl_xor(m, off));
                if (tid == 0) red[0] = m;
            }
            __syncthreads();
            if (tid < S_) aL[tid] = expf(aL[tid] - red[0]);
            __syncthreads();
            if (tid < 64) {
                float sv = aL[tid] + aL[tid + 64];
#pragma unroll
                for (int off = 1; off < 64; off <<= 1) sv += __shfl_xor(sv, off);
                if (tid == 0) red[1] = sv;
            }
            __syncthreads();
            if (tid < S_) aL[tid] = aL[tid] / red[1];
            __syncthreads();
            const float* eb = enc_bt + (size_t)ab * S_ * (2 * H_) + tid * 4;
            float w0 = 0, w1 = 0, w2 = 0, w3 = 0;
            for (int s = 0; s < S_; s++) {
                float a = aL[s];
                float4 v = *(const float4*)(eb + (size_t)s * (2 * H_));
                w0 += a * v.x; w1 += a * v.y; w2 += a * v.z; w3 += a * v.w;
            }
            float4 outv; outv.x = w0; outv.y = w1; outv.z = w2; outv.w = w3;
            *(float4*)(cat_t + (size_t)ab * CATK_ + (H_ + E_) + tid * 4) = outv;
            *(float4*)(wT + (size_t)tid * (B_ * 4) + ab * 4) = outv;   // IDX4(tid*4, ab)
        } else {
            // ghh rows: 96 blocks x 16 rows = 1536; thread = (b, rowgroup)
            const int gb = tid & 31, grg = tid >> 5;
            const int r0 = (bid - 32) * 16 + grg * 2;
#pragma unroll
            for (int rr = 0; rr < 2; rr++) {
                const int r = r0 + rr;
                const float* wrow = dWhh + (size_t)r * H_;
                float acc = 0.f;
                for (int j = 0; j < H_; j += 4) {
                    float4 h4 = *(const float4*)(hin + IDX4(j, gb));
                    float4 w4 = *(const float4*)(wrow + j);
                    acc += h4.x * w4.x + h4.y * w4.y + h4.z * w4.z + h4.w * w4.w;
                }
                ghh[(size_t)r * B_ + gb] = acc + dbhh[r];
            }
        }
        fast_bar128(bars);

        // ---- P2: GRU finish (all blocks; Wih·w k-sliced, half-split) ----
        {
            float p0 = 0.f, p1 = 0.f, p2 = 0.f;
            const int c0 = half * 512;
            for (int c = c0; c < c0 + 512; c += 4) {
                float4 w4 = *(const float4*)(wT + IDX4(c, b));
                float4 r4 = *(const float4*)(wir + c);
                float4 z4 = *(const float4*)(wiz + c);
                float4 n4 = *(const float4*)(win + c);
                p0 += w4.x * r4.x + w4.y * r4.y + w4.z * r4.z + w4.w * r4.w;
                p1 += w4.x * z4.x + w4.y * z4.y + w4.z * z4.z + w4.w * z4.w;
                p2 += w4.x * n4.x + w4.y * n4.y + w4.z * n4.z + w4.w * n4.w;
            }
            part[tid][0] = p0; part[tid][1] = p1; part[tid][2] = p2;
            __syncthreads();
            if (kl < 4) {
                float xr = part[tid][0] + part[tid + 128][0];
                float xz = part[tid][1] + part[tid + 128][1];
                float xn = part[tid][2] + part[tid + 128][2];
                float hr = ghh[(size_t)k * B_ + b];
                float hz = ghh[(size_t)(H_ + k) * B_ + b];
                float hn = ghh[(size_t)(2 * H_ + k) * B_ + b];
                const float* gxe = gx_emb + ((size_t)t * B_ + b) * G3_;
                float rg = 1.f / (1.f + expf(-(gxe[k] + xr + hr)));
                float zg = 1.f / (1.f + expf(-(gxe[H_ + k] + xz + hz)));
                float ng = tanhf(gxe[2 * H_ + k] + xn + rg * hn);
                float hp = hin[IDX4(k, b)];
                float h2 = (1.f - zg) * ng + zg * hp;
                hnext[IDX4(k, b)] = h2;
                cat_t[(size_t)b * CATK_ + k] = h2;
            }
        }
        fast_bar128(bars);
    }
}

// ---------------------------------------------------------------------------
// split cat (fp32 [2016][1792]) into bf16 hi/lo, padded to 2048 rows (zeros)
// ---------------------------------------------------------------------------
__global__ __launch_bounds__(256)
void splitA_kernel(const float* __restrict__ cat,
                   unsigned short* __restrict__ Ahi, unsigned short* __restrict__ Alo)
{
    size_t i4 = ((size_t)blockIdx.x * 256 + threadIdx.x) * 4;
    if (i4 >= (size_t)MPAD_ * CATK_) return;
    size_t row = i4 / CATK_;
    float4 v;
    if (row < (size_t)TD_ * B_) v = *(const float4*)(cat + i4);
    else { v.x = v.y = v.z = v.w = 0.f; }
    float f[4] = {v.x, v.y, v.z, v.w};
    unsigned short h[4], l[4];
#pragma unroll
    for (int j = 0; j < 4; j++) {
        h[j] = bf16_rne(f[j]);
        float hf = __uint_as_float((unsigned)h[j] << 16);
        l[j] = bf16_rne(f[j] - hf);
    }
    *(ushort4*)(Ahi + i4) = make_ushort4(h[0], h[1], h[2], h[3]);
    *(ushort4*)(Alo + i4) = make_ushort4(l[0], l[1], l[2], l[3]);
}

// ---------------------------------------------------------------------------
// fc1 via split-bf16 MFMA (hh + hl + lh): fp32-accurate logits.
// ---------------------------------------------------------------------------
__global__ __launch_bounds__(256)
void fc1_mfma_kernel(const unsigned short* __restrict__ Ahi,
                     const unsigned short* __restrict__ Alo,
                     const float* __restrict__ W,
                     const float* __restrict__ bias,
                     float* __restrict__ C)
{
    __shared__ unsigned short lA[2][128][40];
    __shared__ unsigned short lW[2][128][40];
    const int tid = threadIdx.x;
    const int m0 = blockIdx.x * 128, n0 = blockIdx.y * 128;
    const int w = tid >> 6, lane = tid & 63;
    const int wm = w >> 1, wn = w & 1;
    const int frow = lane & 15, fk = (lane >> 4) * 8;

    f32x4 acc[4][4];
#pragma unroll
    for (int mi = 0; mi < 4; mi++)
#pragma unroll
        for (int ni = 0; ni < 4; ni++) acc[mi][ni] = (f32x4){0.f, 0.f, 0.f, 0.f};

    const int srow = tid >> 1;
    const int skq = (tid & 1) * 16;

    const unsigned short* gAhi = Ahi + (size_t)(m0 + srow) * CATK_ + skq;
    const unsigned short* gAlo = Alo + (size_t)(m0 + srow) * CATK_ + skq;
    const float*          gW   = W   + (size_t)(n0 + srow) * CATK_ + skq;

    int4 rAh0, rAh1, rAl0, rAl1;
    float4 rW0, rW1, rW2, rW3;

#define FC1_LOAD(kb)                                        \
    do {                                                    \
        rAh0 = *(const int4*)(gAhi + (kb));                 \
        rAh1 = *(const int4*)(gAhi + (kb) + 8);             \
        rAl0 = *(const int4*)(gAlo + (kb));                 \
        rAl1 = *(const int4*)(gAlo + (kb) + 8);             \
        rW0  = *(const float4*)(gW + (kb));                 \
        rW1  = *(const float4*)(gW + (kb) + 4);             \
        rW2  = *(const float4*)(gW + (kb) + 8);             \
        rW3  = *(const float4*)(gW + (kb) + 12);            \
    } while (0)

    FC1_LOAD(0);

    for (int kb = 0; kb < CATK_; kb += 32) {
        __syncthreads();
        *(int4*)&lA[0][srow][skq]     = rAh0;
        *(int4*)&lA[0][srow][skq + 8] = rAh1;
        *(int4*)&lA[1][srow][skq]     = rAl0;
        *(int4*)&lA[1][srow][skq + 8] = rAl1;
        {
            float f[16] = {rW0.x, rW0.y, rW0.z, rW0.w, rW1.x, rW1.y, rW1.z, rW1.w,
                           rW2.x, rW2.y, rW2.z, rW2.w, rW3.x, rW3.y, rW3.z, rW3.w};
            unsigned hp[8], lp[8];
#pragma unroll
            for (int j = 0; j < 8; j++) {
                float x0 = f[2 * j], x1 = f[2 * j + 1];
                unsigned short h0 = bf16_rne(x0), h1 = bf16_rne(x1);
                float r0 = x0 - __uint_as_float((unsigned)h0 << 16);
                float r1 = x1 - __uint_as_float((unsigned)h1 << 16);
                hp[j] = (unsigned)h0 | ((unsigned)h1 << 16);
                lp[j] = (unsigned)bf16_rne(r0) | ((unsigned)bf16_rne(r1) << 16);
            }
            *(int4*)&lW[0][srow][skq]     = make_int4(hp[0], hp[1], hp[2], hp[3]);
            *(int4*)&lW[0][srow][skq + 8] = make_int4(hp[4], hp[5], hp[6], hp[7]);
            *(int4*)&lW[1][srow][skq]     = make_int4(lp[0], lp[1], lp[2], lp[3]);
            *(int4*)&lW[1][srow][skq + 8] = make_int4(lp[4], lp[5], lp[6], lp[7]);
        }
        __syncthreads();
        if (kb + 32 < CATK_) FC1_LOAD(kb + 32);

        bf16x8 a[2][4];
#pragma unroll
        for (int mi = 0; mi < 4; mi++) {
            int r = wm * 64 + mi * 16 + frow;
            a[0][mi] = *(const bf16x8*)&lA[0][r][fk];
            a[1][mi] = *(const bf16x8*)&lA[1][r][fk];
        }
#pragma unroll
        for (int ni = 0; ni < 4; ni++) {
            int r = wn * 64 + ni * 16 + frow;
            bf16x8 bh = *(const bf16x8*)&lW[0][r][fk];
            bf16x8 bl = *(const bf16x8*)&lW[1][r][fk];
#pragma unroll
            for (int mi = 0; mi < 4; mi++) {
                acc[mi][ni] = __builtin_amdgcn_mfma_f32_16x16x32_bf16(a[0][mi], bh, acc[mi][ni], 0, 0, 0);
                acc[mi][ni] = __builtin_amdgcn_mfma_f32_16x16x32_bf16(a[1][mi], bh, acc[mi][ni], 0, 0, 0);
                acc[mi][ni] = __builtin_amdgcn_mfma_f32_16x16x32_bf16(a[0][mi], bl, acc[mi][ni], 0, 0, 0);
            }
        }
    }
#undef FC1_LOAD

#pragma unroll
    for (int ni = 0; ni < 4; ni++) {
        int col = n0 + wn * 64 + ni * 16 + frow;
        float bc = bias[col];
#pragma unroll
        for (int mi = 0; mi < 4; mi++) {
            int mbase = m0 + wm * 64 + mi * 16 + (lane >> 4) * 4;
            f32x4 v = acc[mi][ni];
#pragma unroll
            for (int r = 0; r < 4; r++) {
                int m = mbase + r;
                if (m < TD_ * B_) {
                    int tt = m >> 5, bb2 = m & 31;
                    C[((size_t)bb2 * T_ + tt) * V_ + col] = v[r] + bc;
                }
            }
        }
    }
}

// ---------------------------------------------------------------------------
__global__ __launch_bounds__(256)
void argmax_kernel(const float* __restrict__ outp, float* __restrict__ preds)
{
    int row = blockIdx.x;
    int t = row >> 5, b = row & 31;
    const float* p = outp + ((size_t)b * T_ + t) * V_;
    int tid = threadIdx.x;
    float best = -3.4e38f; int bi = V_;
    for (int i = tid; i < V_; i += 256) {
        float v = p[i];
        if (v > best) { best = v; bi = i; }
    }
    __shared__ float bv[256];
    __shared__ int bidx[256];
    bv[tid] = best; bidx[tid] = bi;
    __syncthreads();
    for (int off = 128; off > 0; off >>= 1) {
        if (tid < off) {
            float v2 = bv[tid + off]; int i2 = bidx[tid + off];
            if (v2 > bv[tid] || (v2 == bv[tid] && i2 < bidx[tid])) { bv[tid] = v2; bidx[tid] = i2; }
        }
        __syncthreads();
    }
    if (tid == 0) preds[(size_t)b * T_ + t] = (float)bidx[0];
}

// ---------------------------------------------------------------------------
__global__ __launch_bounds__(256)
void zero_tail_kernel(float* __restrict__ outp, float* __restrict__ preds)
{
    int tid = blockIdx.x * 256 + threadIdx.x;
    if (tid < B_ * V_) {
        int b = tid / V_;
        int c = tid % V_;
        outp[((size_t)b * T_ + (T_ - 1)) * V_ + c] = 0.f;
    }
    if (tid < B_) preds[(size_t)tid * T_ + (T_ - 1)] = 0.f;
}

// ---------------------------------------------------------------------------
extern "C" void kernel_launch(void* const* d_in, const int* in_sizes, int n_in,
                              void* d_out, int out_size, void* d_ws, size_t ws_size,
                              hipStream_t stream)
{
    (void)in_sizes; (void)n_in; (void)out_size;
    const int*   src     = (const int*)d_in[0];
    const int*   tgt     = (const int*)d_in[1];
    const float* enc_emb = (const float*)d_in[2];
    const float* Wih_f   = (const float*)d_in[3];
    const float* Whh_f   = (const float*)d_in[4];
    const float* bih_f   = (const float*)d_in[5];
    const float* bhh_f   = (const float*)d_in[6];
    const float* Wih_b   = (const float*)d_in[7];
    const float* Whh_b   = (const float*)d_in[8];
    const float* bih_b   = (const float*)d_in[9];
    const float* bhh_b   = (const float*)d_in[10];
    const float* fcW     = (const float*)d_in[11];
    const float* fcb     = (const float*)d_in[12];
    const float* dec_emb = (const float*)d_in[13];
    const float* attn_W  = (const float*)d_in[14];
    const float* attn_b  = (const float*)d_in[15];
    const float* attn_v  = (const float*)d_in[16];
    const float* dWih    = (const float*)d_in[17];
    const float* dWhh    = (const float*)d_in[18];
    const float* dbih    = (const float*)d_in[19];
    const float* dbhh    = (const float*)d_in[20];
    const float* fc1W    = (const float*)d_in[21];
    const float* fc1b    = (const float*)d_in[22];
    (void)dbih;

    // workspace layout (all segment sizes multiples of 64 floats -> bars 256B-aligned)
    float* ws     = (float*)d_ws;
    float* cat    = ws;                                  // 3,612,672 f
    float* gx_emb = cat + (size_t)TD_ * B_ * CATK_;      // 3,096,576 f
    float* h_enc  = gx_emb + (size_t)TD_ * B_ * G3_;     // 65,536 f
    float* hT     = h_enc + 2 * 2 * B_ * H_;             // 32,768 f
    float* hwhT   = hT + 2 * H_ * B_;                    // 16,384 f
    float* wT     = hwhT + H_ * B_;                      // 32,768 f
    float* ghh    = wT + 2 * H_ * B_;                    // 49,152 f (1536 x 32)
    int*   tokf   = (int*)(ghh + G3_ * B_);              // 4096 i
    int*   tokb   = tokf + S_ * B_;                      // 4096 i
    int*   tokd   = tokb + S_ * B_;                      // 2016 -> pad 4096
    unsigned* bars = (unsigned*)(tokd + 4096);           // 4096 u (enc @0, dec @2048)
    unsigned short* Ahi = (unsigned short*)(bars + 4096);
    unsigned short* Alo = Ahi + (size_t)MPAD_ * CATK_;
    size_t ws_req = (size_t)((char*)(Alo + (size_t)MPAD_ * CATK_) - (char*)d_ws);
    const bool use_mfma = (ws_size >= ws_req);

    // d_out doubles as phase-local scratch (fully overwritten by fc1 + zero_tail)
    float* dout      = (float*)d_out;
    float* gxf       = dout;
    float* gxb       = dout + (size_t)S_ * B_ * G3_;
    float* enc_bt    = dout + (size_t)2 * S_ * B_ * G3_;
    float* enc_projB = enc_bt + (size_t)B_ * S_ * 2 * H_;
    float* preds     = dout + (size_t)B_ * T_ * V_;

    dim3 thr(256);

    hipLaunchKernelGGL(prep_kernel, dim3(256), thr, 0, stream, src, tgt, tokf, tokb, tokd, h_enc, bars);
    hipLaunchKernelGGL(emb_cat_kernel, dim3(TD_ * B_), thr, 0, stream, tokd, dec_emb, cat);

    hipLaunchKernelGGL((gemm128_kernel<1, 0>), dim3(G3_ / 128, (S_ * B_) / 128), thr, 0, stream,
                       (const float*)nullptr, 0, tokf, enc_emb, Wih_f, E_, bih_f,
                       gxf, G3_, S_ * B_, G3_, E_);
    hipLaunchKernelGGL((gemm128_kernel<1, 0>), dim3(G3_ / 128, (S_ * B_) / 128), thr, 0, stream,
                       (const float*)nullptr, 0, tokb, enc_emb, Wih_b, E_, bih_b,
                       gxb, G3_, S_ * B_, G3_, E_);

    // whole encoder recurrence + enc_fc in ONE launch
    hipLaunchKernelGGL(enc_coop_kernel, dim3(128), thr, 0, stream,
                       gxf, gxb, Whh_f, bhh_f, Whh_b, bhh_b, h_enc, enc_bt,
                       fcW, fcb, hT, bars);

    hipLaunchKernelGGL((gemm128_kernel<0, 0>), dim3(H_ / 128, (B_ * S_) / 128), thr, 0, stream,
                       enc_bt, 2 * H_, (const int*)nullptr, (const float*)nullptr,
                       attn_W + H_, G3_, attn_b, enc_projB, H_, B_ * S_, H_, 2 * H_);

    hipLaunchKernelGGL((gemm128_kernel<1, 0>), dim3(G3_ / 128, (TD_ * B_ + 127) / 128), thr, 0, stream,
                       (const float*)nullptr, 0, tokd, dec_emb, dWih, DIN_, dbih,
                       gx_emb, G3_, TD_ * B_, G3_, E_);

    // whole decoder recurrence in ONE launch
    hipLaunchKernelGGL(dec_coop_kernel, dim3(128), thr, 0, stream,
                       attn_W, attn_v, enc_projB, enc_bt, src,
                       dWhh, dbhh, dWih, gx_emb, cat, hT, hwhT, wT, ghh,
                       bars + 2048);

    if (use_mfma) {
        hipLaunchKernelGGL(splitA_kernel, dim3((MPAD_ * CATK_ / 4 + 255) / 256), thr, 0, stream,
                           cat, Ahi, Alo);
        hipLaunchKernelGGL(fc1_mfma_kernel, dim3(MPAD_ / 128, V_ / 128), thr, 0, stream,
                           Ahi, Alo, fc1W, fc1b, dout);
    } else {
        hipLaunchKernelGGL((gemm128_kernel<0, 1>), dim3(V_ / 128, (TD_ * B_ + 127) / 128), thr, 0, stream,
                           cat, CATK_, (const int*)nullptr, (const float*)nullptr,
                           fc1W, CATK_, fc1b, dout, V_, TD_ * B_, V_, CATK_);
    }

    hipLaunchKernelGGL(argmax_kernel, dim3(TD_ * B_), thr, 0, stream, dout, preds);
    hipLaunchKernelGGL(zero_tail_kernel, dim3((B_ * V_ + 255) / 256), thr, 0, stream, dout, preds);
}

// Round 5
// 8297.192 us; speedup vs baseline: 2.3064x; 1.6099x over previous
//
#include <hip/hip_runtime.h>

#define V_ 32000
#define E_ 256
#define H_ 512
#define B_ 32
#define S_ 128
#define T_ 64
#define TD_ 63        // decoder steps (T-1)
#define G3_ 1536      // 3*H
#define CATK_ 1792    // H + E + 2H
#define DIN_ 1280     // E + 2H
#define MPAD_ 2048    // padded M for fc1 MFMA

typedef __attribute__((ext_vector_type(8))) short bf16x8;
typedef __attribute__((ext_vector_type(4))) float f32x4;

__device__ inline unsigned short bf16_rne(float x) {
    unsigned u = __float_as_uint(x);
    unsigned r = u + 0x7FFFu + ((u >> 16) & 1u);
    return (unsigned short)(r >> 16);
}

// coherence-point (agent-scope) scalar access: bypasses stale L1/L2, NO invalidation
__device__ __forceinline__ float ato_ldf(const float* p) {
    return __hip_atomic_load((const float*)p, __ATOMIC_RELAXED, __HIP_MEMORY_SCOPE_AGENT);
}
__device__ __forceinline__ void ato_stf(float* p, float v) {
    __hip_atomic_store(p, v, __ATOMIC_RELAXED, __HIP_MEMORY_SCOPE_AGENT);
}

// ---------------------------------------------------------------------------
// Fence-FREE hierarchical grid barrier for 128 blocks (8 groups x 16).
// All cross-block data moves via agent-scope atomics, so no cache maintenance
// is needed here. __syncthreads' implicit vmcnt(0) drain orders prior stores.
// ---------------------------------------------------------------------------
__device__ __forceinline__ void fast_bar128(unsigned* bars)
{
    asm volatile("s_waitcnt vmcnt(0)" ::: "memory");
    __syncthreads();
    if (threadIdx.x == 0) {
        const int g = (int)(blockIdx.x >> 4);
        unsigned* gcnt = bars + g * 64;
        unsigned* ggen = gcnt + 32;
        unsigned* tcnt = bars + 512;
        unsigned* tgen = bars + 544;
        unsigned g0 = __hip_atomic_load(ggen, __ATOMIC_RELAXED, __HIP_MEMORY_SCOPE_AGENT);
        unsigned a  = __hip_atomic_fetch_add(gcnt, 1u, __ATOMIC_RELAXED, __HIP_MEMORY_SCOPE_AGENT);
        if (a == 15u) {
            unsigned t0 = __hip_atomic_load(tgen, __ATOMIC_RELAXED, __HIP_MEMORY_SCOPE_AGENT);
            unsigned ta = __hip_atomic_fetch_add(tcnt, 1u, __ATOMIC_RELAXED, __HIP_MEMORY_SCOPE_AGENT);
            if (ta == 7u) {
                __hip_atomic_store(tcnt, 0u, __ATOMIC_RELAXED, __HIP_MEMORY_SCOPE_AGENT);
                __hip_atomic_store(tgen, t0 + 1u, __ATOMIC_RELAXED, __HIP_MEMORY_SCOPE_AGENT);
            } else {
                while (__hip_atomic_load(tgen, __ATOMIC_RELAXED, __HIP_MEMORY_SCOPE_AGENT) == t0)
                    __builtin_amdgcn_s_sleep(1);
            }
            __hip_atomic_store(gcnt, 0u, __ATOMIC_RELAXED, __HIP_MEMORY_SCOPE_AGENT);
            __hip_atomic_store(ggen, g0 + 1u, __ATOMIC_RELAXED, __HIP_MEMORY_SCOPE_AGENT);
        } else {
            while (__hip_atomic_load(ggen, __ATOMIC_RELAXED, __HIP_MEMORY_SCOPE_AGENT) == g0)
                __builtin_amdgcn_s_sleep(1);
        }
    }
    __syncthreads();
}

// ---------------------------------------------------------------------------
// prep: token permutations + zero encoder hidden state + zero barrier region
// ---------------------------------------------------------------------------
__global__ __launch_bounds__(256)
void prep_kernel(const int* __restrict__ src, const int* __restrict__ tgt,
                 int* __restrict__ tokf, int* __restrict__ tokb, int* __restrict__ tokd,
                 float* __restrict__ h_enc, unsigned* __restrict__ bars)
{
    int tid = blockIdx.x * 256 + threadIdx.x;
    if (tid < S_ * B_) {
        int s = tid >> 5, b = tid & 31;
        tokf[tid] = src[b * S_ + s];
        tokb[tid] = src[b * S_ + (S_ - 1 - s)];
    }
    if (tid < TD_ * B_) {
        int t = tid >> 5, b = tid & 31;
        tokd[tid] = tgt[b * T_ + t];
    }
    if (tid < 2 * 2 * B_ * H_) h_enc[tid] = 0.f;   // [dir][pp][B][H]
    if (tid < 4096) bars[tid] = 0u;
}

// ---------------------------------------------------------------------------
// write decoder embeddings into cat[:, 512:768]
// ---------------------------------------------------------------------------
__global__ __launch_bounds__(256)
void emb_cat_kernel(const int* __restrict__ tokd, const float* __restrict__ dec_emb,
                    float* __restrict__ cat)
{
    int row = blockIdx.x;          // row = t*32 + b
    int tid = threadIdx.x;         // 0..255 == E_
    cat[(size_t)row * CATK_ + H_ + tid] = dec_emb[(size_t)tokd[row] * E_ + tid];
}

// ---------------------------------------------------------------------------
// Generic fp32 GEMM (small GEMMs + fallback fc1)
// ---------------------------------------------------------------------------
template<int GATHER, int FC1MAP>
__global__ __launch_bounds__(256)
void gemm128_kernel(const float* __restrict__ A, int lda,
                    const int* __restrict__ tokens, const float* __restrict__ emb,
                    const float* __restrict__ W, int ldw,
                    const float* __restrict__ bias,
                    float* __restrict__ C, int ldc,
                    int M, int N, int K)
{
    __shared__ float As[16][132];
    __shared__ float Ws[16][132];
    (void)N;
    int tid = threadIdx.x;
    int m0 = blockIdx.y * 128, n0 = blockIdx.x * 128;
    int tx = tid & 15, ty = tid >> 4;
    float c[8][8];
#pragma unroll
    for (int i = 0; i < 8; i++)
#pragma unroll
        for (int j = 0; j < 8; j++) c[i][j] = 0.f;

    int arow = tid >> 1;
    int kq = (tid & 1) * 8;

    int am = m0 + arow; if (am >= M) am = M - 1;
    const float* arp;
    if (GATHER) arp = emb + (size_t)tokens[am] * (size_t)K;
    else        arp = A + (size_t)am * (size_t)lda;
    const float* wrp = W + (size_t)(n0 + arow) * (size_t)ldw;

    for (int kb = 0; kb < K; kb += 16) {
        __syncthreads();
        float4 a0 = *(const float4*)(arp + kb + kq);
        float4 a1 = *(const float4*)(arp + kb + kq + 4);
        float4 w0 = *(const float4*)(wrp + kb + kq);
        float4 w1 = *(const float4*)(wrp + kb + kq + 4);
        As[kq + 0][arow] = a0.x; As[kq + 1][arow] = a0.y;
        As[kq + 2][arow] = a0.z; As[kq + 3][arow] = a0.w;
        As[kq + 4][arow] = a1.x; As[kq + 5][arow] = a1.y;
        As[kq + 6][arow] = a1.z; As[kq + 7][arow] = a1.w;
        Ws[kq + 0][arow] = w0.x; Ws[kq + 1][arow] = w0.y;
        Ws[kq + 2][arow] = w0.z; Ws[kq + 3][arow] = w0.w;
        Ws[kq + 4][arow] = w1.x; Ws[kq + 5][arow] = w1.y;
        Ws[kq + 6][arow] = w1.z; Ws[kq + 7][arow] = w1.w;
        __syncthreads();
#pragma unroll
        for (int kk = 0; kk < 16; kk++) {
            float a[8], bb[8];
            *(float4*)&a[0]  = *(const float4*)&As[kk][ty * 8];
            *(float4*)&a[4]  = *(const float4*)&As[kk][ty * 8 + 4];
            *(float4*)&bb[0] = *(const float4*)&Ws[kk][tx * 8];
            *(float4*)&bb[4] = *(const float4*)&Ws[kk][tx * 8 + 4];
#pragma unroll
            for (int i = 0; i < 8; i++)
#pragma unroll
                for (int j = 0; j < 8; j++) c[i][j] += a[i] * bb[j];
        }
    }

#pragma unroll
    for (int i = 0; i < 8; i++) {
        int m = m0 + ty * 8 + i;
        if (m < M) {
            size_t rowoff;
            if (FC1MAP) { int tt = m >> 5, bb2 = m & 31; rowoff = ((size_t)bb2 * T_ + tt) * (size_t)ldc; }
            else        rowoff = (size_t)m * (size_t)ldc;
#pragma unroll
            for (int j = 0; j < 8; j += 4) {
                int n = n0 + tx * 8 + j;
                float4 v;
                v.x = c[i][j + 0] + bias[n + 0];
                v.y = c[i][j + 1] + bias[n + 1];
                v.z = c[i][j + 2] + bias[n + 2];
                v.w = c[i][j + 3] + bias[n + 3];
                *(float4*)(C + rowoff + n) = v;
            }
        }
    }
}

// ---------------------------------------------------------------------------
// PERSISTENT bi-GRU encoder: 128 blocks, fence-free barrier per step.
// Cross-step h state via agent atomics; weights stay L2-resident (no inval).
// Tail: enc_fc distributed -> hT0 laid out [k][b].
// ---------------------------------------------------------------------------
__global__ __launch_bounds__(256)
void enc_coop_kernel(const float* __restrict__ gxf, const float* __restrict__ gxb,
                     const float* __restrict__ Whh_f, const float* __restrict__ bhh_f,
                     const float* __restrict__ Whh_b, const float* __restrict__ bhh_b,
                     float* __restrict__ h_enc, float* __restrict__ enc_bt,
                     const float* __restrict__ fcW, const float* __restrict__ fcb,
                     float* __restrict__ hT0, unsigned* __restrict__ bars)
{
    const int bid = blockIdx.x;
    const int dir = bid >> 6, bh = (bid >> 5) & 1, kc = bid & 31;
    const int tid = threadIdx.x;
    const int bl = tid & 15, kl = tid >> 4;
    const int b = bh * 16 + bl, k = kc * 16 + kl;
    const float* Whh = dir ? Whh_b : Whh_f;
    const float* bhhp = dir ? bhh_b : bhh_f;
    const float* gx  = dir ? gxb : gxf;
    __shared__ float hL[16 * 516];
    const float* wr = Whh + (size_t)k * H_;
    const float* wz = Whh + (size_t)(H_ + k) * H_;
    const float* wn = Whh + (size_t)(2 * H_ + k) * H_;
    const float b_r = bhhp[k], b_z = bhhp[H_ + k], b_n = bhhp[2 * H_ + k];

    for (int t = 0; t < S_; ++t) {
        const int pp = t & 1;
        const float* hin = h_enc + (size_t)(dir * 2 + pp) * B_ * H_;
        float* hout = h_enc + (size_t)(dir * 2 + 1 - pp) * B_ * H_;
        const float* hsrc = hin + (size_t)bh * 16 * H_;
        for (int i = tid; i < 16 * H_; i += 256)
            hL[(i >> 9) * 516 + (i & 511)] = ato_ldf(hsrc + i);
        __syncthreads();
        float ar = 0.f, az = 0.f, an = 0.f;
        const float* hv = &hL[bl * 516];
#pragma unroll 4
        for (int j = 0; j < H_; j += 4) {
            float4 h4 = *(const float4*)(hv + j);
            float4 r4 = *(const float4*)(wr + j);
            float4 z4 = *(const float4*)(wz + j);
            float4 n4 = *(const float4*)(wn + j);
            ar += h4.x * r4.x + h4.y * r4.y + h4.z * r4.z + h4.w * r4.w;
            az += h4.x * z4.x + h4.y * z4.y + h4.z * z4.z + h4.w * z4.w;
            an += h4.x * n4.x + h4.y * n4.y + h4.z * n4.z + h4.w * n4.w;
        }
        const float* gxr = gx + ((size_t)t * B_ + b) * G3_;
        float xr = gxr[k], xz = gxr[H_ + k], xn = gxr[2 * H_ + k];
        float rg = 1.f / (1.f + expf(-(xr + ar + b_r)));
        float zg = 1.f / (1.f + expf(-(xz + az + b_z)));
        float ng = tanhf(xn + rg * (an + b_n));
        float hp = hL[bl * 516 + k];
        float h2 = (1.f - zg) * ng + zg * hp;
        ato_stf(hout + (size_t)b * H_ + k, h2);
        int s_out = dir ? (S_ - 1 - t) : t;
        enc_bt[((size_t)b * S_ + s_out) * (2 * H_) + dir * H_ + k] = h2;
        fast_bar128(bars);
    }

    // tail: hidden = tanh([hf,hb] @ fcW.T + fcb), 128 blocks x 128 rows; hT0[k][b]
    {
        const int b2 = bid & 31, ih = bid >> 5;   // ih in 0..3
        float* hc = hL;
        const float* hf  = h_enc + (size_t)b2 * H_;              // dir0 pp0 (final)
        const float* hbk = h_enc + (size_t)(2 * B_ + b2) * H_;   // dir1 pp0 (final)
        for (int i = tid; i < H_; i += 256) { hc[i] = ato_ldf(hf + i); hc[H_ + i] = ato_ldf(hbk + i); }
        __syncthreads();
        if (tid < 128) {
            int i = ih * 128 + tid;
            const float* w = fcW + (size_t)i * (2 * H_);
            float acc = 0.f;
            for (int j = 0; j < 2 * H_; j += 4) {
                float4 a4 = *(const float4*)&hc[j];
                float4 w4 = *(const float4*)(w + j);
                acc += a4.x * w4.x + a4.y * w4.y + a4.z * w4.z + a4.w * w4.w;
            }
            hT0[(size_t)i * B_ + b2] = tanhf(acc + fcb[i]);
        }
    }
}

// ---------------------------------------------------------------------------
// PERSISTENT attention decoder: 128 blocks, 3 phases/step, fence-free barriers.
// All cross-block data (hT, hwhT, wT, ghh) via agent atomics; weights and
// enc_bt/enc_projB via normal cached loads (stay L2-resident per block).
// Layouts: hT [pp][j*32+b], hwhT [k*32+b], wT [c*32+b], ghh [r*32+b].
// ---------------------------------------------------------------------------
__global__ __launch_bounds__(256)
void dec_coop_kernel(const float* __restrict__ attn_W, const float* __restrict__ attn_v,
                     const float* __restrict__ enc_projB, const float* __restrict__ enc_bt,
                     const int* __restrict__ src,
                     const float* __restrict__ dWhh, const float* __restrict__ dbhh,
                     const float* __restrict__ dWih, const float* __restrict__ gx_emb,
                     float* __restrict__ cat, float* __restrict__ hT,
                     float* __restrict__ hwhT, float* __restrict__ wT,
                     float* __restrict__ ghh, unsigned* __restrict__ bars)
{
    const int bid = blockIdx.x, tid = threadIdx.x;
    __shared__ float smem[16384];      // union: hL 16384 | part 256x13 | attn 1166
    const int b = tid & 31, cc = tid >> 5;      // cc in 0..7
    const int kbase = bid * 4;

    // wave-uniform weight row pointers for this block's 4 k's
    const float* whr0 = attn_W + (size_t)(kbase + 0) * G3_;
    const float* whr1 = attn_W + (size_t)(kbase + 1) * G3_;
    const float* whr2 = attn_W + (size_t)(kbase + 2) * G3_;
    const float* whr3 = attn_W + (size_t)(kbase + 3) * G3_;
    const float* wir[4]; const float* wiz[4]; const float* win[4];
#pragma unroll
    for (int k4 = 0; k4 < 4; k4++) {
        wir[k4] = dWih + (size_t)(kbase + k4) * DIN_ + E_;
        wiz[k4] = dWih + (size_t)(H_ + kbase + k4) * DIN_ + E_;
        win[k4] = dWih + (size_t)(2 * H_ + kbase + k4) * DIN_ + E_;
    }

    for (int t = 0; t < TD_; ++t) {
        const int pp = t & 1;
        const float* hin = hT + (size_t)pp * (H_ * B_);
        float* hnext = hT + (size_t)(1 - pp) * (H_ * B_);
        float* cat_t = cat + (size_t)t * B_ * CATK_;

        // ---- P0: hwhT[k][b] for this block's 4 k's; (b, cc)-split, LDS combine ----
        {
            float s0 = 0.f, s1 = 0.f, s2 = 0.f, s3 = 0.f;
            const int j0 = cc * 64;
            for (int j = j0; j < j0 + 64; ++j) {
                float hvv = ato_ldf(hin + (size_t)j * B_ + b);
                s0 += hvv * whr0[j]; s1 += hvv * whr1[j];
                s2 += hvv * whr2[j]; s3 += hvv * whr3[j];
            }
            float* part = smem;   // [256][5]
            part[tid * 5 + 0] = s0; part[tid * 5 + 1] = s1;
            part[tid * 5 + 2] = s2; part[tid * 5 + 3] = s3;
            __syncthreads();
            if (tid < 128) {
                int bb = tid & 31, k4 = tid >> 5;
                float acc = 0.f;
#pragma unroll
                for (int c2 = 0; c2 < 8; c2++) acc += part[(c2 * 32 + bb) * 5 + k4];
                ato_stf(hwhT + (size_t)(kbase + k4) * B_ + bb, acc);
            }
        }
        fast_bar128(bars);

        // ---- P1: attention (blocks 0..31) | ghh = Whh·h + bhh (blocks 32..127) ----
        if (bid < 32) {
            const int ab = bid;
            float* hwh = smem;            // 512
            float* vL  = smem + 512;      // 512
            float* aL  = smem + 1024;     // 128
            float* red = smem + 1152;     // 2
            for (int i = tid; i < H_; i += 256) {
                hwh[i] = ato_ldf(hwhT + (size_t)i * B_ + ab);
                vL[i]  = attn_v[i];
            }
            __syncthreads();
            int wv = tid >> 6, lane = tid & 63;
            for (int so = 0; so < 32; so++) {
                int s = so * 4 + wv;
                const float* pr = enc_projB + ((size_t)ab * S_ + s) * H_;
                float acc = 0.f;
#pragma unroll
                for (int u = 0; u < 8; u++) {
                    int hh = u * 64 + lane;
                    float x = hwh[hh] + pr[hh];
                    float e2 = __expf(2.f * x);
                    acc += vL[hh] * (1.f - 2.f / (e2 + 1.f));
                }
#pragma unroll
                for (int off = 1; off < 64; off <<= 1) acc += __shfl_xor(acc, off);
                if (lane == 0) aL[s] = acc;
            }
            __syncthreads();
            if (tid < S_) aL[tid] = (src[ab * S_ + tid] != 0) ? aL[tid] : -1e10f;
            __syncthreads();
            if (tid < 64) {
                float m = fmaxf(aL[tid], aL[tid + 64]);
#pragma unroll
                for (int off = 1; off < 64; off <<= 1) m = fmaxf(m, __shfl_xor(m, off));
                if (tid == 0) red[0] = m;
            }
            __syncthreads();
            if (tid < S_) aL[tid] = expf(aL[tid] - red[0]);
            __syncthreads();
            if (tid < 64) {
                float sv = aL[tid] + aL[tid + 64];
#pragma unroll
                for (int off = 1; off < 64; off <<= 1) sv += __shfl_xor(sv, off);
                if (tid == 0) red[1] = sv;
            }
            __syncthreads();
            if (tid < S_) aL[tid] = aL[tid] / red[1];
            __syncthreads();
            const float* eb = enc_bt + (size_t)ab * S_ * (2 * H_) + tid * 4;
            float w0 = 0, w1 = 0, w2 = 0, w3 = 0;
            for (int s = 0; s < S_; s++) {
                float a = aL[s];
                float4 v = *(const float4*)(eb + (size_t)s * (2 * H_));
                w0 += a * v.x; w1 += a * v.y; w2 += a * v.z; w3 += a * v.w;
            }
            float4 outv; outv.x = w0; outv.y = w1; outv.z = w2; outv.w = w3;
            *(float4*)(cat_t + (size_t)ab * CATK_ + (H_ + E_) + tid * 4) = outv;
            ato_stf(wT + (size_t)(tid * 4 + 0) * B_ + ab, w0);
            ato_stf(wT + (size_t)(tid * 4 + 1) * B_ + ab, w1);
            ato_stf(wT + (size_t)(tid * 4 + 2) * B_ + ab, w2);
            ato_stf(wT + (size_t)(tid * 4 + 3) * B_ + ab, w3);
        } else {
            // ghh: 96 blocks x 16 rows; stage h into LDS once (16K atomic loads)
            float* hL = smem;   // [512][32]
            for (int i = tid; i < H_ * B_; i += 256) hL[i] = ato_ldf(hin + i);
            __syncthreads();
            const int gb = tid & 31, grg = tid >> 5;
            const int r0 = (bid - 32) * 16 + grg * 2;
            const float* wrow0 = dWhh + (size_t)r0 * H_;
            const float* wrow1 = wrow0 + H_;
            float a0 = 0.f, a1 = 0.f;
            for (int j = 0; j < H_; ++j) {
                float hvv = hL[j * B_ + gb];
                a0 += hvv * wrow0[j];
                a1 += hvv * wrow1[j];
            }
            ato_stf(ghh + (size_t)r0 * B_ + gb, a0 + dbhh[r0]);
            ato_stf(ghh + (size_t)(r0 + 1) * B_ + gb, a1 + dbhh[r0 + 1]);
        }
        fast_bar128(bars);

        // ---- P2: xr/xz/xn = Wih·w (b, cc)-split; combine + gate math ----
        {
            float s[12];
#pragma unroll
            for (int i = 0; i < 12; i++) s[i] = 0.f;
            const int c0 = cc * 128;
            for (int c = c0; c < c0 + 128; ++c) {
                float wv = ato_ldf(wT + (size_t)c * B_ + b);
#pragma unroll
                for (int k4 = 0; k4 < 4; k4++) {
                    s[k4 * 3 + 0] += wv * wir[k4][c];
                    s[k4 * 3 + 1] += wv * wiz[k4][c];
                    s[k4 * 3 + 2] += wv * win[k4][c];
                }
            }
            float* part = smem;   // [256][13]
#pragma unroll
            for (int i = 0; i < 12; i++) part[tid * 13 + i] = s[i];
            __syncthreads();
            if (tid < 128) {
                int bb = tid & 31, k4 = tid >> 5;
                int k = kbase + k4;
                float xr = 0.f, xz = 0.f, xn = 0.f;
#pragma unroll
                for (int c2 = 0; c2 < 8; c2++) {
                    int pi = (c2 * 32 + bb) * 13 + k4 * 3;
                    xr += part[pi + 0]; xz += part[pi + 1]; xn += part[pi + 2];
                }
                float hr = ato_ldf(ghh + (size_t)k * B_ + bb);
                float hz = ato_ldf(ghh + (size_t)(H_ + k) * B_ + bb);
                float hn = ato_ldf(ghh + (size_t)(2 * H_ + k) * B_ + bb);
                const float* gxe = gx_emb + ((size_t)t * B_ + bb) * G3_;
                float rg = 1.f / (1.f + expf(-(gxe[k] + xr + hr)));
                float zg = 1.f / (1.f + expf(-(gxe[H_ + k] + xz + hz)));
                float ng = tanhf(gxe[2 * H_ + k] + xn + rg * hn);
                float hp = ato_ldf(hin + (size_t)k * B_ + bb);
                float h2 = (1.f - zg) * ng + zg * hp;
                ato_stf(hnext + (size_t)k * B_ + bb, h2);
                cat_t[(size_t)bb * CATK_ + k] = h2;
            }
        }
        fast_bar128(bars);
    }
}

// ---------------------------------------------------------------------------
// split cat (fp32 [2016][1792]) into bf16 hi/lo, padded to 2048 rows (zeros)
// ---------------------------------------------------------------------------
__global__ __launch_bounds__(256)
void splitA_kernel(const float* __restrict__ cat,
                   unsigned short* __restrict__ Ahi, unsigned short* __restrict__ Alo)
{
    size_t i4 = ((size_t)blockIdx.x * 256 + threadIdx.x) * 4;
    if (i4 >= (size_t)MPAD_ * CATK_) return;
    size_t row = i4 / CATK_;
    float4 v;
    if (row < (size_t)TD_ * B_) v = *(const float4*)(cat + i4);
    else { v.x = v.y = v.z = v.w = 0.f; }
    float f[4] = {v.x, v.y, v.z, v.w};
    unsigned short h[4], l[4];
#pragma unroll
    for (int j = 0; j < 4; j++) {
        h[j] = bf16_rne(f[j]);
        float hf = __uint_as_float((unsigned)h[j] << 16);
        l[j] = bf16_rne(f[j] - hf);
    }
    *(ushort4*)(Ahi + i4) = make_ushort4(h[0], h[1], h[2], h[3]);
    *(ushort4*)(Alo + i4) = make_ushort4(l[0], l[1], l[2], l[3]);
}

// ---------------------------------------------------------------------------
// fc1 via split-bf16 MFMA (hh + hl + lh): fp32-accurate logits.
// ---------------------------------------------------------------------------
__global__ __launch_bounds__(256)
void fc1_mfma_kernel(const unsigned short* __restrict__ Ahi,
                     const unsigned short* __restrict__ Alo,
                     const float* __restrict__ W,
                     const float* __restrict__ bias,
                     float* __restrict__ C)
{
    __shared__ unsigned short lA[2][128][40];
    __shared__ unsigned short lW[2][128][40];
    const int tid = threadIdx.x;
    const int m0 = blockIdx.x * 128, n0 = blockIdx.y * 128;
    const int w = tid >> 6, lane = tid & 63;
    const int wm = w >> 1, wn = w & 1;
    const int frow = lane & 15, fk = (lane >> 4) * 8;

    f32x4 acc[4][4];
#pragma unroll
    for (int mi = 0; mi < 4; mi++)
#pragma unroll
        for (int ni = 0; ni < 4; ni++) acc[mi][ni] = (f32x4){0.f, 0.f, 0.f, 0.f};

    const int srow = tid >> 1;
    const int skq = (tid & 1) * 16;

    const unsigned short* gAhi = Ahi + (size_t)(m0 + srow) * CATK_ + skq;
    const unsigned short* gAlo = Alo + (size_t)(m0 + srow) * CATK_ + skq;
    const float*          gW   = W   + (size_t)(n0 + srow) * CATK_ + skq;

    int4 rAh0, rAh1, rAl0, rAl1;
    float4 rW0, rW1, rW2, rW3;

#define FC1_LOAD(kb)                                        \
    do {                                                    \
        rAh0 = *(const int4*)(gAhi + (kb));                 \
        rAh1 = *(const int4*)(gAhi + (kb) + 8);             \
        rAl0 = *(const int4*)(gAlo + (kb));                 \
        rAl1 = *(const int4*)(gAlo + (kb) + 8);             \
        rW0  = *(const float4*)(gW + (kb));                 \
        rW1  = *(const float4*)(gW + (kb) + 4);             \
        rW2  = *(const float4*)(gW + (kb) + 8);             \
        rW3  = *(const float4*)(gW + (kb) + 12);            \
    } while (0)

    FC1_LOAD(0);

    for (int kb = 0; kb < CATK_; kb += 32) {
        __syncthreads();
        *(int4*)&lA[0][srow][skq]     = rAh0;
        *(int4*)&lA[0][srow][skq + 8] = rAh1;
        *(int4*)&lA[1][srow][skq]     = rAl0;
        *(int4*)&lA[1][srow][skq + 8] = rAl1;
        {
            float f[16] = {rW0.x, rW0.y, rW0.z, rW0.w, rW1.x, rW1.y, rW1.z, rW1.w,
                           rW2.x, rW2.y, rW2.z, rW2.w, rW3.x, rW3.y, rW3.z, rW3.w};
            unsigned hp[8], lp[8];
#pragma unroll
            for (int j = 0; j < 8; j++) {
                float x0 = f[2 * j], x1 = f[2 * j + 1];
                unsigned short h0 = bf16_rne(x0), h1 = bf16_rne(x1);
                float r0 = x0 - __uint_as_float((unsigned)h0 << 16);
                float r1 = x1 - __uint_as_float((unsigned)h1 << 16);
                hp[j] = (unsigned)h0 | ((unsigned)h1 << 16);
                lp[j] = (unsigned)bf16_rne(r0) | ((unsigned)bf16_rne(r1) << 16);
            }
            *(int4*)&lW[0][srow][skq]     = make_int4(hp[0], hp[1], hp[2], hp[3]);
            *(int4*)&lW[0][srow][skq + 8] = make_int4(hp[4], hp[5], hp[6], hp[7]);
            *(int4*)&lW[1][srow][skq]     = make_int4(lp[0], lp[1], lp[2], lp[3]);
            *(int4*)&lW[1][srow][skq + 8] = make_int4(lp[4], lp[5], lp[6], lp[7]);
        }
        __syncthreads();
        if (kb + 32 < CATK_) FC1_LOAD(kb + 32);

        bf16x8 a[2][4];
#pragma unroll
        for (int mi = 0; mi < 4; mi++) {
            int r = wm * 64 + mi * 16 + frow;
            a[0][mi] = *(const bf16x8*)&lA[0][r][fk];
            a[1][mi] = *(const bf16x8*)&lA[1][r][fk];
        }
#pragma unroll
        for (int ni = 0; ni < 4; ni++) {
            int r = wn * 64 + ni * 16 + frow;
            bf16x8 bh = *(const bf16x8*)&lW[0][r][fk];
            bf16x8 bl = *(const bf16x8*)&lW[1][r][fk];
#pragma unroll
            for (int mi = 0; mi < 4; mi++) {
                acc[mi][ni] = __builtin_amdgcn_mfma_f32_16x16x32_bf16(a[0][mi], bh, acc[mi][ni], 0, 0, 0);
                acc[mi][ni] = __builtin_amdgcn_mfma_f32_16x16x32_bf16(a[1][mi], bh, acc[mi][ni], 0, 0, 0);
                acc[mi][ni] = __builtin_amdgcn_mfma_f32_16x16x32_bf16(a[0][mi], bl, acc[mi][ni], 0, 0, 0);
            }
        }
    }
#undef FC1_LOAD

#pragma unroll
    for (int ni = 0; ni < 4; ni++) {
        int col = n0 + wn * 64 + ni * 16 + frow;
        float bc = bias[col];
#pragma unroll
        for (int mi = 0; mi < 4; mi++) {
            int mbase = m0 + wm * 64 + mi * 16 + (lane >> 4) * 4;
            f32x4 v = acc[mi][ni];
#pragma unroll
            for (int r = 0; r < 4; r++) {
                int m = mbase + r;
                if (m < TD_ * B_) {
                    int tt = m >> 5, bb2 = m & 31;
                    C[((size_t)bb2 * T_ + tt) * V_ + col] = v[r] + bc;
                }
            }
        }
    }
}

// ---------------------------------------------------------------------------
__global__ __launch_bounds__(256)
void argmax_kernel(const float* __restrict__ outp, float* __restrict__ preds)
{
    int row = blockIdx.x;
    int t = row >> 5, b = row & 31;
    const float* p = outp + ((size_t)b * T_ + t) * V_;
    int tid = threadIdx.x;
    float best = -3.4e38f; int bi = V_;
    for (int i = tid; i < V_; i += 256) {
        float v = p[i];
        if (v > best) { best = v; bi = i; }
    }
    __shared__ float bv[256];
    __shared__ int bidx[256];
    bv[tid] = best; bidx[tid] = bi;
    __syncthreads();
    for (int off = 128; off > 0; off >>= 1) {
        if (tid < off) {
            float v2 = bv[tid + off]; int i2 = bidx[tid + off];
            if (v2 > bv[tid] || (v2 == bv[tid] && i2 < bidx[tid])) { bv[tid] = v2; bidx[tid] = i2; }
        }
        __syncthreads();
    }
    if (tid == 0) preds[(size_t)b * T_ + t] = (float)bidx[0];
}

// ---------------------------------------------------------------------------
__global__ __launch_bounds__(256)
void zero_tail_kernel(float* __restrict__ outp, float* __restrict__ preds)
{
    int tid = blockIdx.x * 256 + threadIdx.x;
    if (tid < B_ * V_) {
        int b = tid / V_;
        int c = tid % V_;
        outp[((size_t)b * T_ + (T_ - 1)) * V_ + c] = 0.f;
    }
    if (tid < B_) preds[(size_t)tid * T_ + (T_ - 1)] = 0.f;
}

// ---------------------------------------------------------------------------
extern "C" void kernel_launch(void* const* d_in, const int* in_sizes, int n_in,
                              void* d_out, int out_size, void* d_ws, size_t ws_size,
                              hipStream_t stream)
{
    (void)in_sizes; (void)n_in; (void)out_size;
    const int*   src     = (const int*)d_in[0];
    const int*   tgt     = (const int*)d_in[1];
    const float* enc_emb = (const float*)d_in[2];
    const float* Wih_f   = (const float*)d_in[3];
    const float* Whh_f   = (const float*)d_in[4];
    const float* bih_f   = (const float*)d_in[5];
    const float* bhh_f   = (const float*)d_in[6];
    const float* Wih_b   = (const float*)d_in[7];
    const float* Whh_b   = (const float*)d_in[8];
    const float* bih_b   = (const float*)d_in[9];
    const float* bhh_b   = (const float*)d_in[10];
    const float* fcW     = (const float*)d_in[11];
    const float* fcb     = (const float*)d_in[12];
    const float* dec_emb = (const float*)d_in[13];
    const float* attn_W  = (const float*)d_in[14];
    const float* attn_b  = (const float*)d_in[15];
    const float* attn_v  = (const float*)d_in[16];
    const float* dWih    = (const float*)d_in[17];
    const float* dWhh    = (const float*)d_in[18];
    const float* dbih    = (const float*)d_in[19];
    const float* dbhh    = (const float*)d_in[20];
    const float* fc1W    = (const float*)d_in[21];
    const float* fc1b    = (const float*)d_in[22];
    (void)dbih;

    // workspace layout (segments multiple of 64 floats -> bars 256B-aligned)
    float* ws     = (float*)d_ws;
    float* cat    = ws;                                  // 3,612,672 f
    float* gx_emb = cat + (size_t)TD_ * B_ * CATK_;      // 3,096,576 f
    float* h_enc  = gx_emb + (size_t)TD_ * B_ * G3_;     // 65,536 f
    float* hT     = h_enc + 2 * 2 * B_ * H_;             // 32,768 f ([pp][k*32+b])
    float* hwhT   = hT + 2 * H_ * B_;                    // 16,384 f ([k*32+b])
    float* wT     = hwhT + H_ * B_;                      // 32,768 f ([c*32+b])
    float* ghh    = wT + 2 * H_ * B_;                    // 49,152 f ([r*32+b])
    int*   tokf   = (int*)(ghh + G3_ * B_);              // 4096 i
    int*   tokb   = tokf + S_ * B_;                      // 4096 i
    int*   tokd   = tokb + S_ * B_;                      // 2016 -> pad 4096
    unsigned* bars = (unsigned*)(tokd + 4096);           // 4096 u (enc @0, dec @2048)
    unsigned short* Ahi = (unsigned short*)(bars + 4096);
    unsigned short* Alo = Ahi + (size_t)MPAD_ * CATK_;
    size_t ws_req = (size_t)((char*)(Alo + (size_t)MPAD_ * CATK_) - (char*)d_ws);
    const bool use_mfma = (ws_size >= ws_req);

    // d_out doubles as phase-local scratch (fully overwritten by fc1 + zero_tail)
    float* dout      = (float*)d_out;
    float* gxf       = dout;
    float* gxb       = dout + (size_t)S_ * B_ * G3_;
    float* enc_bt    = dout + (size_t)2 * S_ * B_ * G3_;
    float* enc_projB = enc_bt + (size_t)B_ * S_ * 2 * H_;
    float* preds     = dout + (size_t)B_ * T_ * V_;

    dim3 thr(256);

    hipLaunchKernelGGL(prep_kernel, dim3(256), thr, 0, stream, src, tgt, tokf, tokb, tokd, h_enc, bars);
    hipLaunchKernelGGL(emb_cat_kernel, dim3(TD_ * B_), thr, 0, stream, tokd, dec_emb, cat);

    hipLaunchKernelGGL((gemm128_kernel<1, 0>), dim3(G3_ / 128, (S_ * B_) / 128), thr, 0, stream,
                       (const float*)nullptr, 0, tokf, enc_emb, Wih_f, E_, bih_f,
                       gxf, G3_, S_ * B_, G3_, E_);
    hipLaunchKernelGGL((gemm128_kernel<1, 0>), dim3(G3_ / 128, (S_ * B_) / 128), thr, 0, stream,
                       (const float*)nullptr, 0, tokb, enc_emb, Wih_b, E_, bih_b,
                       gxb, G3_, S_ * B_, G3_, E_);

    // whole encoder recurrence + enc_fc in ONE launch
    hipLaunchKernelGGL(enc_coop_kernel, dim3(128), thr, 0, stream,
                       gxf, gxb, Whh_f, bhh_f, Whh_b, bhh_b, h_enc, enc_bt,
                       fcW, fcb, hT, bars);

    hipLaunchKernelGGL((gemm128_kernel<0, 0>), dim3(H_ / 128, (B_ * S_) / 128), thr, 0, stream,
                       enc_bt, 2 * H_, (const int*)nullptr, (const float*)nullptr,
                       attn_W + H_, G3_, attn_b, enc_projB, H_, B_ * S_, H_, 2 * H_);

    hipLaunchKernelGGL((gemm128_kernel<1, 0>), dim3(G3_ / 128, (TD_ * B_ + 127) / 128), thr, 0, stream,
                       (const float*)nullptr, 0, tokd, dec_emb, dWih, DIN_, dbih,
                       gx_emb, G3_, TD_ * B_, G3_, E_);

    // whole decoder recurrence in ONE launch
    hipLaunchKernelGGL(dec_coop_kernel, dim3(128), thr, 0, stream,
                       attn_W, attn_v, enc_projB, enc_bt, src,
                       dWhh, dbhh, dWih, gx_emb, cat, hT, hwhT, wT, ghh,
                       bars + 2048);

    if (use_mfma) {
        hipLaunchKernelGGL(splitA_kernel, dim3((MPAD_ * CATK_ / 4 + 255) / 256), thr, 0, stream,
                           cat, Ahi, Alo);
        hipLaunchKernelGGL(fc1_mfma_kernel, dim3(MPAD_ / 128, V_ / 128), thr, 0, stream,
                           Ahi, Alo, fc1W, fc1b, dout);
    } else {
        hipLaunchKernelGGL((gemm128_kernel<0, 1>), dim3(V_ / 128, (TD_ * B_ + 127) / 128), thr, 0, stream,
                           cat, CATK_, (const int*)nullptr, (const float*)nullptr,
                           fc1W, CATK_, fc1b, dout, V_, TD_ * B_, V_, CATK_);
    }

    hipLaunchKernelGGL(argmax_kernel, dim3(TD_ * B_), thr, 0, stream, dout, preds);
    hipLaunchKernelGGL(zero_tail_kernel, dim3((B_ * V_ + 255) / 256), thr, 0, stream, dout, preds);
}